// Round 1
// baseline (1326.386 us; speedup 1.0000x reference)
//
#include <hip/hip_runtime.h>

// GINModel on MI355X (gfx950). Round 7:
//  - NEW fused_layer_k: fuses the per-layer GEMM pair (Linear-ReLU-Linear) into
//    one persistent kernel. h1 intermediate lives entirely in LDS (no 51MB
//    HBM round-trip per layer). Transposed-operand MFMA so accumulators pack
//    to b64 LDS writes; XOR-16B swizzle keeps all LDS ops at the bank floor.
//    Register prefetch of the next A-tile (T14 split) + 2-region LDS role swap.
//    BN stats stay fused in the epilogue.
//  - old gemm_k retained for the small predictor GEMM only.
// fp16 internal storage, fp32 accumulation, dual-width input hardening.

typedef __attribute__((ext_vector_type(4))) float f32x4;
typedef __attribute__((ext_vector_type(8))) _Float16 f16x8;

__device__ __forceinline__ float h2f(unsigned short u) {
  _Float16 h; __builtin_memcpy(&h, &u, 2); return (float)h;
}
__device__ __forceinline__ unsigned short f2h16(float f) {
  _Float16 h = (_Float16)f; unsigned short u; __builtin_memcpy(&u, &h, 2); return u;
}
__device__ __forceinline__ unsigned short f2b(float f) {  // fp32 -> bf16 RNE
  union { float f; unsigned int i; } c; c.f = f;
  unsigned int x = c.i;
  return (unsigned short)((x + 0x7fffu + ((x >> 16) & 1u)) >> 16);
}
__device__ __forceinline__ float lin(const void* p, long long i, int wf32) {
  if (wf32) return ((const float*)p)[i];
  union { unsigned int i; float f; } c;
  c.i = ((unsigned int)((const unsigned short*)p)[i]) << 16;
  return c.f;
}
__device__ __forceinline__ int ldidx(const int* p, long long i, int w64) {
  return w64 ? p[2 * i] : p[i];
}

// flags[0]=w64 (int64 indices), flags[1]=wf32 (fp32 floats)
__global__ void detect_k(const int* __restrict__ edge, const unsigned short* __restrict__ xa,
                         int* __restrict__ flags) {
  if (threadIdx.x != 0 || blockIdx.x != 0) return;
  int nzOdd = 0;
  for (int t = 0; t < 256; t++) if (edge[2 * t + 1] != 0) nzOdd++;
  flags[0] = (nzOdd == 0) ? 1 : 0;
  int plaus = 0;
  for (int t = 0; t < 64; t++) {
    unsigned short w = xa[2 * t];
    int e = (w >> 7) & 0xFF;
    if (w == 0 || (e >= 0x70 && e <= 0x85)) plaus++;
  }
  flags[1] = (plaus < 32) ? 1 : 0;
}

__global__ void zero_i32_k(int* __restrict__ p, int n) {
  int i = blockIdx.x * blockDim.x + threadIdx.x;
  if (i < n) p[i] = 0;
}

// per-layer prep: slice 4x256 params to fp32 + zero BN accumulators (512 f32)
__global__ void prep_k(const void* __restrict__ b1, const void* __restrict__ b2,
                       const void* __restrict__ gm, const void* __restrict__ bt, int eoff,
                       float* __restrict__ pb1, float* __restrict__ pb2,
                       float* __restrict__ pg, float* __restrict__ pb,
                       float* __restrict__ gsum, const int* __restrict__ flags) {
  int wf32 = flags[1], t = threadIdx.x;
  pb1[t] = lin(b1, (long long)eoff + t, wf32);
  pb2[t] = lin(b2, (long long)eoff + t, wf32);
  pg[t]  = lin(gm, (long long)eoff + t, wf32);
  pb[t]  = lin(bt, (long long)eoff + t, wf32);
  gsum[t] = 0.f; gsum[256 + t] = 0.f;
}
__global__ void copy256_k(const void* __restrict__ src, int eoff, float* __restrict__ dst,
                          const int* __restrict__ flags) {
  dst[threadIdx.x] = lin(src, (long long)eoff + threadIdx.x, flags[1]);
}

// input (R x C at element offset, dual width) -> fp16 transposed (C x R)
__global__ void transpose_off_k(const void* __restrict__ src, long long eoff,
                                unsigned short* __restrict__ dst, int R, int C,
                                const int* __restrict__ flags) {
  int wf32 = flags[1];
  __shared__ unsigned short t[32][33];
  int bx = blockIdx.x * 32, by = blockIdx.y * 32;
  int x = bx + threadIdx.x;
  for (int i = 0; i < 32; i += 8) {
    int y = by + threadIdx.y + i;
    if (y < R && x < C)
      t[threadIdx.y + i][threadIdx.x] = f2h16(lin(src, eoff + (long long)y * C + x, wf32));
  }
  __syncthreads();
  int x2 = by + threadIdx.x;
  for (int i = 0; i < 32; i += 8) {
    int y = bx + threadIdx.y + i;
    if (y < C && x2 < R) dst[(long long)y * R + x2] = t[threadIdx.x][threadIdx.y + i];
  }
}

// ---------------- CSR ----------------
__global__ void hist_k(const int* __restrict__ edge, int E, int* __restrict__ cnt,
                       const int* __restrict__ flags) {
  int w64 = flags[0];
  int e = blockIdx.x * blockDim.x + threadIdx.x;
  if (e < E) atomicAdd(&cnt[ldidx(edge, (long long)E + e, w64)], 1);
}
#define SCAN_CHUNK 1024
__global__ void scan1_k(const int* __restrict__ in, int* __restrict__ out,
                        int* __restrict__ partials, int n) {
  __shared__ int sh[256];
  int tid = threadIdx.x;
  int base = blockIdx.x * SCAN_CHUNK + tid * 4;
  int v[4]; int tsum = 0;
#pragma unroll
  for (int i = 0; i < 4; i++) { v[i] = (base + i < n) ? in[base + i] : 0; tsum += v[i]; }
  sh[tid] = tsum; __syncthreads();
  for (int off = 1; off < 256; off <<= 1) {
    int t = (tid >= off) ? sh[tid - off] : 0;
    __syncthreads();
    sh[tid] += t;
    __syncthreads();
  }
  int run = sh[tid] - tsum;
#pragma unroll
  for (int i = 0; i < 4; i++) { if (base + i < n) out[base + i] = run; run += v[i]; }
  if (tid == 255) partials[blockIdx.x] = sh[255];
}
__global__ void scan2_k(int* partials, int B) {
  __shared__ int sh[256];
  int tid = threadIdx.x;
  int orig = (tid < B) ? partials[tid] : 0;
  sh[tid] = orig; __syncthreads();
  for (int off = 1; off < 256; off <<= 1) {
    int t = (tid >= off) ? sh[tid - off] : 0;
    __syncthreads();
    sh[tid] += t;
    __syncthreads();
  }
  if (tid < B) partials[tid] = sh[tid] - orig;
}
__global__ void scan3_k(int* __restrict__ out, const int* __restrict__ partials,
                        int n, int total) {
  int base = blockIdx.x * SCAN_CHUNK + threadIdx.x * 4;
  int add = partials[blockIdx.x];
#pragma unroll
  for (int i = 0; i < 4; i++) { if (base + i < n) out[base + i] += add; }
  if (blockIdx.x == 0 && threadIdx.x == 0) out[n] = total;
}
__global__ void fill_k(const int* __restrict__ edge, int E, const int* __restrict__ rowptr,
                       int* __restrict__ cnt, int* __restrict__ colidx,
                       const int* __restrict__ flags) {
  int w64 = flags[0];
  int e = blockIdx.x * blockDim.x + threadIdx.x;
  if (e >= E) return;
  int s = ldidx(edge, e, w64);
  int d = ldidx(edge, (long long)E + e, w64);
  int p = atomicAdd(&cnt[d], 1);
  colidx[rowptr[d] + p] = s;
}
__global__ void graph_bounds_k(const int* __restrict__ b, int Nn, int G,
                               int* __restrict__ gstart, const int* __restrict__ flags) {
  int w64 = flags[0];
  int g = blockIdx.x * blockDim.x + threadIdx.x;
  if (g > G) return;
  int lo = 0, hi = Nn;
  while (lo < hi) {
    int mid = (lo + hi) >> 1;
    if (ldidx(b, mid, w64) < g) lo = mid + 1; else hi = mid;
  }
  gstart[g] = lo;
}

// x (dual width) -> fp16
__global__ void convert_k(const void* __restrict__ x, unsigned short* __restrict__ xh,
                          long long n, const int* __restrict__ flags) {
  int wf32 = flags[1];
  long long base = ((long long)blockIdx.x * blockDim.x + threadIdx.x) * 4;
  if (base >= n) return;
#pragma unroll
  for (int k = 0; k < 4; k++) xh[base + k] = f2h16(lin(x, base + k, wf32));
}

// fused aggregation: u[i] = hn(i) + sum_{j in nbrs(i)} hn(j)
// hn = APPLY ? relu(v*scale+shift) : v.  LPN lanes per node, 8 fp16 per lane.
template <int LPN, int APPLY>
__global__ void gather_fused_k(const unsigned short* __restrict__ src,
                               const float* __restrict__ scale, const float* __restrict__ shift,
                               const int* __restrict__ rowptr, const int* __restrict__ colidx,
                               unsigned short* __restrict__ u, int Nn) {
  const int F = LPN * 8;
  int gid = blockIdx.x * blockDim.x + threadIdx.x;
  int node = gid / LPN;
  if (node >= Nn) return;
  int fb = (gid % LPN) * 8;
  float sc[8], sh[8];
  if (APPLY) {
#pragma unroll
    for (int k = 0; k < 8; k++) { sc[k] = scale[fb + k]; sh[k] = shift[fb + k]; }
  }
  float acc[8];
  {
    uint4 raw = *(const uint4*)(src + (long long)node * F + fb);
    unsigned int ws[4] = {raw.x, raw.y, raw.z, raw.w};
#pragma unroll
    for (int k = 0; k < 8; k++) {
      float xv = h2f((unsigned short)((ws[k >> 1] >> ((k & 1) * 16)) & 0xffff));
      acc[k] = APPLY ? fmaxf(xv * sc[k] + sh[k], 0.f) : xv;
    }
  }
  int s = rowptr[node], e = rowptr[node + 1];
  for (int j = s; j < e; j++) {
    long long nb = colidx[j];
    uint4 raw = *(const uint4*)(src + nb * F + fb);
    unsigned int ws[4] = {raw.x, raw.y, raw.z, raw.w};
#pragma unroll
    for (int k = 0; k < 8; k++) {
      float xv = h2f((unsigned short)((ws[k >> 1] >> ((k & 1) * 16)) & 0xffff));
      acc[k] += APPLY ? fmaxf(xv * sc[k] + sh[k], 0.f) : xv;
    }
  }
  uint4 o;
  unsigned int wo[4];
#pragma unroll
  for (int p = 0; p < 4; p++)
    wo[p] = (unsigned int)f2h16(acc[2 * p]) | ((unsigned int)f2h16(acc[2 * p + 1]) << 16);
  o.x = wo[0]; o.y = wo[1]; o.z = wo[2]; o.w = wo[3];
  *(uint4*)(u + (long long)node * F + fb) = o;
}

// =====================================================================
// fused_layer_k: per-layer v = (relu(u@W1+b1))@W2 + b2, + BN column stats.
// Persistent: 256 blocks (1/CU), 512 threads (8 waves), LDS 2x64KB regions.
// Region roles per tile t (128 rows): Rp = A(t) -> h1(t) -> v-staging -> BN
// scratch; Rq = destination for reg-prefetched A(t+1).
// Both MFMA stages computed transposed (A-op = W rows, B-op = data rows) so
// each lane's 4 accum values are 4 consecutive cols of one row -> b64 packs.
// All LDS regions: linear 2*K-byte rows, 16B chunks XOR-swizzled by (row&7)
// -> every b128/b64 access at the 32-bank data-movement floor.
// Wave grid: wn = wave>>1 (n-quarter of 256), wm = wave&1 (m-half of 128).
// =====================================================================
template <int KIN>
__global__ __launch_bounds__(512, 2) void fused_layer_k(
    const unsigned short* __restrict__ A, const unsigned short* __restrict__ W1t,
    const unsigned short* __restrict__ W2t, const float* __restrict__ b1,
    const float* __restrict__ b2, unsigned short* __restrict__ V,
    int M, int ntiles, float* __restrict__ gsum) {
  __shared__ __align__(16) unsigned char lds_raw[131072];
  const int tid = threadIdx.x;
  const int lane = tid & 63, wave = tid >> 6;
  const int l15 = lane & 15, lq = lane >> 4;
  const int wn = wave >> 1, wm = wave & 1;
  const int nb0 = wn * 64, mb0 = wm * 64;
  constexpr int KT1 = KIN / 32;       // stage-1 k-tiles (4 or 8); also uint4/thread
  const int srow = tid >> 2;          // staging row 0..127
  const int sc0 = tid & 3;            // staging chunk phase

  // ---- prologue: stage A(tile blockIdx.x) into region 0 ----
  if ((int)blockIdx.x < ntiles) {
    long long m0 = (long long)blockIdx.x * 128;
    long long row = m0 + srow; if (row >= M) row = M - 1;
    const unsigned short* ps = A + row * KIN + sc0 * 8;
#pragma unroll
    for (int j = 0; j < KT1; j++) {
      int c = sc0 + 4 * j;
      uint4 v = *(const uint4*)(ps + 32 * j);
      *(uint4*)(lds_raw + srow * (2 * KIN) + 16 * (c ^ (srow & 7))) = v;
    }
  }
  __syncthreads();

  unsigned char* Rp = lds_raw;
  unsigned char* Rq = lds_raw + 65536;
  for (int t = blockIdx.x; t < ntiles; t += 256) {
    long long m0 = (long long)t * 128;
    int tn = t + 256;
    bool hasNext = tn < ntiles;
    // reg-prefetch next A tile (survives barriers; written to Rq after bar1)
    uint4 pre[KT1];
    if (hasNext) {
      long long rowN = (long long)tn * 128 + srow;
      if (rowN >= M) rowN = M - 1;
      const unsigned short* ps = A + rowN * KIN + sc0 * 8;
#pragma unroll
      for (int j = 0; j < KT1; j++) pre[j] = *(const uint4*)(ps + 32 * j);
    }
    // ---- stage 1: h1T[n][m] = relu((u @ W1)^T + b1) ----
    f32x4 acc[4][4] = {};
#pragma unroll
    for (int kt = 0; kt < KT1; kt++) {
      f16x8 wf[4], uf[4];
#pragma unroll
      for (int r = 0; r < 4; r++)
        wf[r] = *(const f16x8*)(W1t + (long long)(nb0 + 16 * r + l15) * KIN + kt * 32 + lq * 8);
#pragma unroll
      for (int c = 0; c < 4; c++) {
        int m = mb0 + 16 * c + l15;
        uf[c] = *(const f16x8*)(Rp + m * (2 * KIN) + 16 * ((kt * 4 + lq) ^ (m & 7)));
      }
#pragma unroll
      for (int r = 0; r < 4; r++)
#pragma unroll
        for (int c = 0; c < 4; c++)
          acc[r][c] = __builtin_amdgcn_mfma_f32_16x16x32_f16(wf[r], uf[c], acc[r][c], 0, 0, 0);
    }
    __syncthreads();  // bar1: all stage-1 reads of Rp done
    // h1 -> Rp (row m, 512B stride, swizzled); bias + relu
#pragma unroll
    for (int r = 0; r < 4; r++) {
      int nbase = nb0 + 16 * r + lq * 4;
      float4 bv = *(const float4*)(b1 + nbase);
#pragma unroll
      for (int c = 0; c < 4; c++) {
        int m = mb0 + 16 * c + l15;
        unsigned int h0 = f2h16(fmaxf(acc[r][c][0] + bv.x, 0.f));
        unsigned int h1v = f2h16(fmaxf(acc[r][c][1] + bv.y, 0.f));
        unsigned int h2v = f2h16(fmaxf(acc[r][c][2] + bv.z, 0.f));
        unsigned int h3 = f2h16(fmaxf(acc[r][c][3] + bv.w, 0.f));
        uint2 pk; pk.x = h0 | (h1v << 16); pk.y = h2v | (h3 << 16);
        int by = m * 512 + 16 * ((nbase >> 3) ^ (m & 7)) + ((nbase & 7) << 1);
        *(uint2*)(Rp + by) = pk;
      }
    }
    // A(t+1) regs -> Rq (region idle since previous tile's BN reduce)
    if (hasNext) {
#pragma unroll
      for (int j = 0; j < KT1; j++) {
        int c = sc0 + 4 * j;
        *(uint4*)(Rq + srow * (2 * KIN) + 16 * (c ^ (srow & 7))) = pre[j];
      }
    }
    __syncthreads();  // bar2: h1 + next-A visible
    // ---- stage 2: vT[n][m] = (h1 @ W2)^T + b2 ----
    f32x4 acc2[4][4] = {};
#pragma unroll
    for (int kt = 0; kt < 8; kt++) {
      f16x8 wf[4], hf[4];
#pragma unroll
      for (int r = 0; r < 4; r++)
        wf[r] = *(const f16x8*)(W2t + (long long)(nb0 + 16 * r + l15) * 256 + kt * 32 + lq * 8);
#pragma unroll
      for (int c = 0; c < 4; c++) {
        int m = mb0 + 16 * c + l15;
        hf[c] = *(const f16x8*)(Rp + m * 512 + 16 * ((kt * 4 + lq) ^ (m & 7)));
      }
#pragma unroll
      for (int r = 0; r < 4; r++)
#pragma unroll
        for (int c = 0; c < 4; c++)
          acc2[r][c] = __builtin_amdgcn_mfma_f32_16x16x32_f16(wf[r], hf[c], acc2[r][c], 0, 0, 0);
    }
    __syncthreads();  // bar3: all stage-2 reads of h1 done
    // v -> Rp ([m][n], swizzled); bias, no relu
#pragma unroll
    for (int r = 0; r < 4; r++) {
      int nbase = nb0 + 16 * r + lq * 4;
      float4 bv = *(const float4*)(b2 + nbase);
#pragma unroll
      for (int c = 0; c < 4; c++) {
        int m = mb0 + 16 * c + l15;
        unsigned int h0 = f2h16(acc2[r][c][0] + bv.x);
        unsigned int h1v = f2h16(acc2[r][c][1] + bv.y);
        unsigned int h2v = f2h16(acc2[r][c][2] + bv.z);
        unsigned int h3 = f2h16(acc2[r][c][3] + bv.w);
        uint2 pk; pk.x = h0 | (h1v << 16); pk.y = h2v | (h3 << 16);
        int by = m * 512 + 16 * ((nbase >> 3) ^ (m & 7)) + ((nbase & 7) << 1);
        *(uint2*)(Rp + by) = pk;
      }
    }
    __syncthreads();  // bar4: v tile complete
    // coalesced store + BN partials
    const int c32 = tid & 31, rg = tid >> 5;
    float s8[8] = {}, q8[8] = {};
#pragma unroll
    for (int k = 0; k < 8; k++) {
      int m = rg * 8 + k;
      uint4 vw = *(const uint4*)(Rp + m * 512 + 16 * (c32 ^ (m & 7)));
      long long grow = m0 + m;
      if (grow < M) {
        *(uint4*)(V + grow * 256 + c32 * 8) = vw;
        unsigned int ws[4] = {vw.x, vw.y, vw.z, vw.w};
#pragma unroll
        for (int kk = 0; kk < 8; kk++) {
          float xv = h2f((unsigned short)((ws[kk >> 1] >> ((kk & 1) * 16)) & 0xffff));
          s8[kk] += xv; q8[kk] += xv * xv;
        }
      }
    }
    __syncthreads();  // bar5: v reads done; Rp reusable as scratch
    float* shf = (float*)Rp;  // [256][17] sums + [256][17] sumsq = 34816 B
#pragma unroll
    for (int kk = 0; kk < 8; kk++) {
      int col = c32 * 8 + kk;
      shf[col * 17 + rg] = s8[kk];
      shf[4352 + col * 17 + rg] = q8[kk];
    }
    __syncthreads();  // bar6
    if (tid < 256) {
      float tot = 0.f;
#pragma unroll
      for (int g = 0; g < 16; g++) tot += shf[tid * 17 + g];
      atomicAdd(&gsum[tid], tot);
    } else {
      int col = tid - 256; float tot = 0.f;
#pragma unroll
      for (int g = 0; g < 16; g++) tot += shf[4352 + col * 17 + g];
      atomicAdd(&gsum[256 + col], tot);
    }
    unsigned char* tmp = Rp; Rp = Rq; Rq = tmp;  // Rq(A(t+1)) becomes Rp
  }
}

// MFMA fp16 GEMM (predictor only). Tile 128x128, BK=32, 4 waves.
#define SA 40    // padded A/B staging stride (fp16)
#define SP 136   // padded C-tile stride (fp16)
__global__ __launch_bounds__(256) void gemm_k(
    const unsigned short* __restrict__ A, const unsigned short* __restrict__ Bt,
    const float* __restrict__ bias, unsigned short* __restrict__ C,
    int M, int K, int relu, float* __restrict__ gsum) {
  __shared__ __align__(16) unsigned short smem[128 * SP];
  unsigned short* As = smem;
  unsigned short* Bs = smem + 128 * SA;
  int m0 = blockIdx.x * 128, n0 = blockIdx.y * 128;
  int tid = threadIdx.x;
  int wave = tid >> 6, lane = tid & 63;
  int wm = (wave >> 1) * 64, wnn = (wave & 1) * 64;
  int lrow = lane & 15, lqq = lane >> 4;
  f32x4 acc[4][4] = {};
  int ktiles = K >> 5;
  int srow = tid >> 2;
  int ch8 = (tid & 3) << 3;
  int rowA0 = m0 + srow;      rowA0 = rowA0 < M ? rowA0 : M - 1;
  int rowA1 = m0 + srow + 64; rowA1 = rowA1 < M ? rowA1 : M - 1;
  const unsigned short* pa0 = A + (long long)rowA0 * K + ch8;
  const unsigned short* pa1 = A + (long long)rowA1 * K + ch8;
  const unsigned short* pq0 = Bt + (long long)(n0 + srow) * K + ch8;
  const unsigned short* pq1 = Bt + (long long)(n0 + srow + 64) * K + ch8;
  uint4 va0 = *(const uint4*)pa0, va1 = *(const uint4*)pa1;
  uint4 vb0 = *(const uint4*)pq0, vb1 = *(const uint4*)pq1;
  int lo0 = srow * SA + ch8, lo1 = (srow + 64) * SA + ch8;
  for (int kt = 0; kt < ktiles; ++kt) {
    __syncthreads();
    *(uint4*)(As + lo0) = va0;
    *(uint4*)(As + lo1) = va1;
    *(uint4*)(Bs + lo0) = vb0;
    *(uint4*)(Bs + lo1) = vb1;
    __syncthreads();
    f16x8 af[4], bf[4];
#pragma unroll
    for (int r = 0; r < 4; r++)
      af[r] = *(const f16x8*)(As + (wm + 16 * r + lrow) * SA + lqq * 8);
#pragma unroll
    for (int c = 0; c < 4; c++)
      bf[c] = *(const f16x8*)(Bs + (wnn + 16 * c + lrow) * SA + lqq * 8);
    if (kt + 1 < ktiles) {
      int kb = (kt + 1) << 5;
      va0 = *(const uint4*)(pa0 + kb); va1 = *(const uint4*)(pa1 + kb);
      vb0 = *(const uint4*)(pq0 + kb); vb1 = *(const uint4*)(pq1 + kb);
    }
#pragma unroll
    for (int r = 0; r < 4; r++)
#pragma unroll
      for (int c = 0; c < 4; c++)
        acc[r][c] = __builtin_amdgcn_mfma_f32_16x16x32_f16(af[r], bf[c], acc[r][c], 0, 0, 0);
  }
  __syncthreads();
  unsigned short* Ct = smem;
#pragma unroll
  for (int c = 0; c < 4; c++) {
    int col = wnn + 16 * c + lrow;
    float bv = bias[n0 + col];
#pragma unroll
    for (int r = 0; r < 4; r++) {
      int rbase = wm + 16 * r + lqq * 4;
#pragma unroll
      for (int i = 0; i < 4; i++) {
        float v = acc[r][c][i] + bv;
        if (relu) v = fmaxf(v, 0.f);
        Ct[(rbase + i) * SP + col] = f2h16(v);
      }
    }
  }
  __syncthreads();
  int c16 = tid & 15, g = tid >> 4;
  float s8[8] = {}, q8[8] = {};
  bool dostats = (gsum != nullptr);
#pragma unroll
  for (int i = 0; i < 8; i++) {
    int row = g + i * 16;
    int grow = m0 + row;
    uint4 vw = *(const uint4*)(Ct + row * SP + c16 * 8);
    if (grow < M) {
      *(uint4*)(C + (long long)grow * 256 + n0 + c16 * 8) = vw;
      if (dostats) {
        unsigned int ws[4] = {vw.x, vw.y, vw.z, vw.w};
#pragma unroll
        for (int k = 0; k < 8; k++) {
          float xv = h2f((unsigned short)((ws[k >> 1] >> ((k & 1) * 16)) & 0xffff));
          s8[k] += xv; q8[k] += xv * xv;
        }
      }
    }
  }
  if (dostats) {
    float* shf = (float*)smem;
    __syncthreads();
#pragma unroll
    for (int k = 0; k < 8; k++) shf[(c16 * 8 + k) * 17 + g] = s8[k];
    __syncthreads();
    if (tid < 128) {
      float t = 0.f;
#pragma unroll
      for (int gg = 0; gg < 16; gg++) t += shf[tid * 17 + gg];
      atomicAdd(&gsum[n0 + tid], t);
    }
    __syncthreads();
#pragma unroll
    for (int k = 0; k < 8; k++) shf[(c16 * 8 + k) * 17 + g] = q8[k];
    __syncthreads();
    if (tid < 128) {
      float t = 0.f;
#pragma unroll
      for (int gg = 0; gg < 16; gg++) t += shf[tid * 17 + gg];
      atomicAdd(&gsum[256 + n0 + tid], t);
    }
  }
}

__global__ void bn_finalize_k(const float* __restrict__ gsum,
                              const float* __restrict__ pg, const float* __restrict__ pb,
                              int Nn, float* __restrict__ scale, float* __restrict__ shift) {
  int f = threadIdx.x;
  float inv = 1.f / (float)Nn;
  float mean = gsum[f] * inv;
  float var = fmaxf(gsum[256 + f] * inv - mean * mean, 0.f);
  float sc = pg[f] * rsqrtf(var + 1e-5f);
  scale[f] = sc;
  shift[f] = pb[f] - mean * sc;
}

// fused pool: mean over graph rows of relu(v*sc+sh)
__global__ void pool_fused_k(const unsigned short* __restrict__ v, const float* __restrict__ scale,
                             const float* __restrict__ shift, const int* __restrict__ gstart,
                             unsigned short* __restrict__ gout) {
  int g = blockIdx.x, f = threadIdx.x;
  int s = gstart[g], e = gstart[g + 1];
  float sc = scale[f], sh = shift[f];
  float acc = 0.f;
  for (int r = s; r < e; r++) acc += fmaxf(h2f(v[(long long)r * 256 + f]) * sc + sh, 0.f);
  gout[(long long)g * 256 + f] = f2h16(acc / fmaxf((float)(e - s), 1.f));
}
__global__ void pred2_k(const unsigned short* __restrict__ p1, const void* __restrict__ Wp2,
                        const void* __restrict__ bp2, void* __restrict__ out, int G,
                        const int* __restrict__ flags) {
  int wf32 = flags[1];
  int idx = blockIdx.x * blockDim.x + threadIdx.x;
  if (idx >= G * 12) return;
  int g = idx / 12, t = idx - g * 12;
  float acc = lin(bp2, t, wf32);
  const unsigned short* row = p1 + (long long)g * 256;
  for (int k = 0; k < 256; k++) acc += h2f(row[k]) * lin(Wp2, k * 12 + t, wf32);
  if (wf32) ((float*)out)[idx] = acc;
  else      ((unsigned short*)out)[idx] = f2b(acc);
}

extern "C" void kernel_launch(void* const* d_in, const int* in_sizes, int n_in,
                              void* d_out, int out_size, void* d_ws, size_t ws_size,
                              hipStream_t stream) {
  int wb = -1;
  for (int i = 3; i + 15 < n_in; i++) {
    if (in_sizes[i] == 32768 && in_sizes[i + 1] == 256 && in_sizes[i + 2] == 65536 &&
        in_sizes[i + 3] == 256 && in_sizes[i + 4] == 256 && in_sizes[i + 5] == 256 &&
        in_sizes[i + 6] == 262144) { wb = i; break; }
  }
  if (wb < 0) wb = (n_in >= 20) ? 4 : 3;

  const void* x      = d_in[0];
  const int*  edge   = (const int*)d_in[1];
  const int*  batch  = (const int*)d_in[2];
  const void* W1_0   = d_in[wb + 0];
  const void* b1_0   = d_in[wb + 1];
  const void* W2_0   = d_in[wb + 2];
  const void* b2_0   = d_in[wb + 3];
  const void* gamma0 = d_in[wb + 4];
  const void* beta0  = d_in[wb + 5];
  const void* W1s    = d_in[wb + 6];
  const void* b1s    = d_in[wb + 7];
  const void* W2s    = d_in[wb + 8];
  const void* b2s    = d_in[wb + 9];
  const void* gammas = d_in[wb + 10];
  const void* betas  = d_in[wb + 11];
  const void* Wp1    = d_in[wb + 12];
  const void* bp1    = d_in[wb + 13];
  const void* Wp2    = d_in[wb + 14];
  const void* bp2    = d_in[wb + 15];

  const int N = in_sizes[0] / 128;
  const int E = in_sizes[1] / 2;
  const int G = out_size / 12;
  const int H = 256;

  char* w = (char*)d_ws;
  size_t off = 0;
  auto alloc = [&](size_t bytes) -> char* {
    char* p = w + off;
    off += (bytes + 255) & ~(size_t)255;
    return p;
  };
  unsigned short* bufX  = (unsigned short*)alloc((size_t)N * H * 2);
  unsigned short* bufY  = (unsigned short*)alloc((size_t)N * H * 2);  // xh parks here first
  unsigned short* w1_0t = (unsigned short*)alloc((size_t)128 * 256 * 2);
  unsigned short* w2_0t = (unsigned short*)alloc((size_t)256 * 256 * 2);
  unsigned short* w1st  = (unsigned short*)alloc((size_t)4 * 256 * 256 * 2);
  unsigned short* w2st  = (unsigned short*)alloc((size_t)4 * 256 * 256 * 2);
  unsigned short* wp1t  = (unsigned short*)alloc((size_t)256 * 256 * 2);
  int*   rowptr   = (int*)alloc((size_t)(N + 1) * 4);
  int*   cnt      = (int*)alloc((size_t)N * 4);
  int*   colidx   = (int*)alloc((size_t)E * 4);
  int*   partials = (int*)alloc(1024 * 4);
  float* gsum     = (float*)alloc(512 * 4);
  float* bnscale  = (float*)alloc(256 * 4);
  float* bnshift  = (float*)alloc(256 * 4);
  float* pg       = (float*)alloc(256 * 4);
  float* pb       = (float*)alloc(256 * 4);
  float* pb1      = (float*)alloc(256 * 4);
  float* pb2      = (float*)alloc(256 * 4);
  int*   gstart   = (int*)alloc((size_t)(G + 1) * 4);
  int*   flags    = (int*)alloc(256);
  unsigned short* gpool = (unsigned short*)alloc((size_t)G * H * 2);
  unsigned short* p1    = (unsigned short*)alloc((size_t)G * H * 2);
  (void)ws_size; (void)n_in;

  detect_k<<<1, 64, 0, stream>>>(edge, (const unsigned short*)x, flags);

  // x -> fp16 into bufY (dead once layer-0 fused kernel overwrites bufY)
  convert_k<<<(int)(((long long)N * 128 / 4 + 255) / 256), 256, 0, stream>>>(
      x, bufY, (long long)N * 128, flags);

  dim3 tb(32, 8);
  auto transpose = [&](const void* src, long long eoff, unsigned short* dst, int R, int C) {
    transpose_off_k<<<dim3((C + 31) / 32, (R + 31) / 32), tb, 0, stream>>>(src, eoff, dst, R, C, flags);
  };
  transpose(W1_0, 0, w1_0t, 128, 256);
  transpose(W2_0, 0, w2_0t, 256, 256);
  for (int i = 0; i < 4; i++) {
    transpose(W1s, (long long)i * 65536, w1st + i * 65536, 256, 256);
    transpose(W2s, (long long)i * 65536, w2st + i * 65536, 256, 256);
  }
  transpose(Wp1, 0, wp1t, 256, 256);

  // CSR
  zero_i32_k<<<(N + 255) / 256, 256, 0, stream>>>(cnt, N);
  hist_k<<<(E + 255) / 256, 256, 0, stream>>>(edge, E, cnt, flags);
  int NB = (N + SCAN_CHUNK - 1) / SCAN_CHUNK;
  scan1_k<<<NB, 256, 0, stream>>>(cnt, rowptr, partials, N);
  scan2_k<<<1, 256, 0, stream>>>(partials, NB);
  scan3_k<<<NB, 256, 0, stream>>>(rowptr, partials, N, E);
  zero_i32_k<<<(N + 255) / 256, 256, 0, stream>>>(cnt, N);
  fill_k<<<(E + 255) / 256, 256, 0, stream>>>(edge, E, rowptr, cnt, colidx, flags);
  graph_bounds_k<<<(G + 1 + 255) / 256, 256, 0, stream>>>(batch, N, G, gstart, flags);

  const int ntiles = (N + 127) / 128;
  auto fused = [&](const unsigned short* Au, const unsigned short* w1, const unsigned short* w2,
                   unsigned short* Vv, int K) {
    if (K == 128)
      fused_layer_k<128><<<256, 512, 0, stream>>>(Au, w1, w2, pb1, pb2, Vv, N, ntiles, gsum);
    else
      fused_layer_k<256><<<256, 512, 0, stream>>>(Au, w1, w2, pb1, pb2, Vv, N, ntiles, gsum);
  };

  // ---- layer 0 ----
  prep_k<<<1, 256, 0, stream>>>(b1_0, b2_0, gamma0, beta0, 0, pb1, pb2, pg, pb, gsum, flags);
  gather_fused_k<16, 0><<<(N * 16 + 255) / 256, 256, 0, stream>>>(
      bufY, bnscale, bnshift, rowptr, colidx, bufX, N);
  fused(bufX, w1_0t, w2_0t, bufY, 128);   // v0 + fused BN stats -> bufY
  bn_finalize_k<<<1, 256, 0, stream>>>(gsum, pg, pb, N, bnscale, bnshift);
  unsigned short* cur = bufY;  // pre-BN v0
  unsigned short* oth = bufX;
  // ---- layers 1..4 ----
  for (int i = 0; i < 4; i++) {
    prep_k<<<1, 256, 0, stream>>>(b1s, b2s, gammas, betas, i * 256, pb1, pb2, pg, pb, gsum, flags);
    gather_fused_k<32, 1><<<(N * 32 + 255) / 256, 256, 0, stream>>>(
        cur, bnscale, bnshift, rowptr, colidx, oth, N);
    fused(oth, w1st + i * 65536, w2st + i * 65536, cur, 256);  // v_i + BN stats -> cur
    bn_finalize_k<<<1, 256, 0, stream>>>(gsum, pg, pb, N, bnscale, bnshift);
  }

  // ---- pool + predictor ----
  copy256_k<<<1, 256, 0, stream>>>(bp1, 0, pb1, flags);
  pool_fused_k<<<G, 256, 0, stream>>>(cur, bnscale, bnshift, gstart, gpool);
  gemm_k<<<dim3((G + 127) / 128, 2), 256, 0, stream>>>(gpool, wp1t, pb1, p1, G, 256, 1, nullptr);
  pred2_k<<<(G * 12 + 255) / 256, 256, 0, stream>>>(p1, Wp2, bp2, d_out, G, flags);
}

// Round 2
// 1133.222 us; speedup vs baseline: 1.1705x; 1.1705x over previous
//
#include <hip/hip_runtime.h>

// GINModel on MI355X (gfx950). Round 8:
//  - fused_layer_k round-7 post-mortem: reg-prefetch of next A-tile (pre[8],
//    32 VGPRs live across stage-1 MFMA) blew the 128-VGPR budget -> scratch
//    spills (131MB extra HBM traffic each direction). Fix: prefetch via
//    __builtin_amdgcn_global_load_lds (width 16) directly into Rq with
//    linear LDS dest + inverse-XOR-swizzled per-lane global source (rule #21
//    both-sides-or-neither). Zero prefetch registers; staging ds_writes gone.
//  - everything else unchanged from round 7.
// fp16 internal storage, fp32 accumulation, dual-width input hardening.

typedef __attribute__((ext_vector_type(4))) float f32x4;
typedef __attribute__((ext_vector_type(8))) _Float16 f16x8;

__device__ __forceinline__ float h2f(unsigned short u) {
  _Float16 h; __builtin_memcpy(&h, &u, 2); return (float)h;
}
__device__ __forceinline__ unsigned short f2h16(float f) {
  _Float16 h = (_Float16)f; unsigned short u; __builtin_memcpy(&u, &h, 2); return u;
}
__device__ __forceinline__ unsigned short f2b(float f) {  // fp32 -> bf16 RNE
  union { float f; unsigned int i; } c; c.f = f;
  unsigned int x = c.i;
  return (unsigned short)((x + 0x7fffu + ((x >> 16) & 1u)) >> 16);
}
__device__ __forceinline__ float lin(const void* p, long long i, int wf32) {
  if (wf32) return ((const float*)p)[i];
  union { unsigned int i; float f; } c;
  c.i = ((unsigned int)((const unsigned short*)p)[i]) << 16;
  return c.f;
}
__device__ __forceinline__ int ldidx(const int* p, long long i, int w64) {
  return w64 ? p[2 * i] : p[i];
}

// async global->LDS, 16B per lane; LDS dest = wave-uniform base + lane*16
__device__ __forceinline__ void gload_lds16(const void* g, void* l) {
  __builtin_amdgcn_global_load_lds(
      (const __attribute__((address_space(1))) unsigned int*)g,
      (__attribute__((address_space(3))) unsigned int*)l, 16, 0, 0);
}

// flags[0]=w64 (int64 indices), flags[1]=wf32 (fp32 floats)
__global__ void detect_k(const int* __restrict__ edge, const unsigned short* __restrict__ xa,
                         int* __restrict__ flags) {
  if (threadIdx.x != 0 || blockIdx.x != 0) return;
  int nzOdd = 0;
  for (int t = 0; t < 256; t++) if (edge[2 * t + 1] != 0) nzOdd++;
  flags[0] = (nzOdd == 0) ? 1 : 0;
  int plaus = 0;
  for (int t = 0; t < 64; t++) {
    unsigned short w = xa[2 * t];
    int e = (w >> 7) & 0xFF;
    if (w == 0 || (e >= 0x70 && e <= 0x85)) plaus++;
  }
  flags[1] = (plaus < 32) ? 1 : 0;
}

__global__ void zero_i32_k(int* __restrict__ p, int n) {
  int i = blockIdx.x * blockDim.x + threadIdx.x;
  if (i < n) p[i] = 0;
}

// per-layer prep: slice 4x256 params to fp32 + zero BN accumulators (512 f32)
__global__ void prep_k(const void* __restrict__ b1, const void* __restrict__ b2,
                       const void* __restrict__ gm, const void* __restrict__ bt, int eoff,
                       float* __restrict__ pb1, float* __restrict__ pb2,
                       float* __restrict__ pg, float* __restrict__ pb,
                       float* __restrict__ gsum, const int* __restrict__ flags) {
  int wf32 = flags[1], t = threadIdx.x;
  pb1[t] = lin(b1, (long long)eoff + t, wf32);
  pb2[t] = lin(b2, (long long)eoff + t, wf32);
  pg[t]  = lin(gm, (long long)eoff + t, wf32);
  pb[t]  = lin(bt, (long long)eoff + t, wf32);
  gsum[t] = 0.f; gsum[256 + t] = 0.f;
}
__global__ void copy256_k(const void* __restrict__ src, int eoff, float* __restrict__ dst,
                          const int* __restrict__ flags) {
  dst[threadIdx.x] = lin(src, (long long)eoff + threadIdx.x, flags[1]);
}

// input (R x C at element offset, dual width) -> fp16 transposed (C x R)
__global__ void transpose_off_k(const void* __restrict__ src, long long eoff,
                                unsigned short* __restrict__ dst, int R, int C,
                                const int* __restrict__ flags) {
  int wf32 = flags[1];
  __shared__ unsigned short t[32][33];
  int bx = blockIdx.x * 32, by = blockIdx.y * 32;
  int x = bx + threadIdx.x;
  for (int i = 0; i < 32; i += 8) {
    int y = by + threadIdx.y + i;
    if (y < R && x < C)
      t[threadIdx.y + i][threadIdx.x] = f2h16(lin(src, eoff + (long long)y * C + x, wf32));
  }
  __syncthreads();
  int x2 = by + threadIdx.x;
  for (int i = 0; i < 32; i += 8) {
    int y = bx + threadIdx.y + i;
    if (y < C && x2 < R) dst[(long long)y * R + x2] = t[threadIdx.x][threadIdx.y + i];
  }
}

// ---------------- CSR ----------------
__global__ void hist_k(const int* __restrict__ edge, int E, int* __restrict__ cnt,
                       const int* __restrict__ flags) {
  int w64 = flags[0];
  int e = blockIdx.x * blockDim.x + threadIdx.x;
  if (e < E) atomicAdd(&cnt[ldidx(edge, (long long)E + e, w64)], 1);
}
#define SCAN_CHUNK 1024
__global__ void scan1_k(const int* __restrict__ in, int* __restrict__ out,
                        int* __restrict__ partials, int n) {
  __shared__ int sh[256];
  int tid = threadIdx.x;
  int base = blockIdx.x * SCAN_CHUNK + tid * 4;
  int v[4]; int tsum = 0;
#pragma unroll
  for (int i = 0; i < 4; i++) { v[i] = (base + i < n) ? in[base + i] : 0; tsum += v[i]; }
  sh[tid] = tsum; __syncthreads();
  for (int off = 1; off < 256; off <<= 1) {
    int t = (tid >= off) ? sh[tid - off] : 0;
    __syncthreads();
    sh[tid] += t;
    __syncthreads();
  }
  int run = sh[tid] - tsum;
#pragma unroll
  for (int i = 0; i < 4; i++) { if (base + i < n) out[base + i] = run; run += v[i]; }
  if (tid == 255) partials[blockIdx.x] = sh[255];
}
__global__ void scan2_k(int* partials, int B) {
  __shared__ int sh[256];
  int tid = threadIdx.x;
  int orig = (tid < B) ? partials[tid] : 0;
  sh[tid] = orig; __syncthreads();
  for (int off = 1; off < 256; off <<= 1) {
    int t = (tid >= off) ? sh[tid - off] : 0;
    __syncthreads();
    sh[tid] += t;
    __syncthreads();
  }
  if (tid < B) partials[tid] = sh[tid] - orig;
}
__global__ void scan3_k(int* __restrict__ out, const int* __restrict__ partials,
                        int n, int total) {
  int base = blockIdx.x * SCAN_CHUNK + threadIdx.x * 4;
  int add = partials[blockIdx.x];
#pragma unroll
  for (int i = 0; i < 4; i++) { if (base + i < n) out[base + i] += add; }
  if (blockIdx.x == 0 && threadIdx.x == 0) out[n] = total;
}
__global__ void fill_k(const int* __restrict__ edge, int E, const int* __restrict__ rowptr,
                       int* __restrict__ cnt, int* __restrict__ colidx,
                       const int* __restrict__ flags) {
  int w64 = flags[0];
  int e = blockIdx.x * blockDim.x + threadIdx.x;
  if (e >= E) return;
  int s = ldidx(edge, e, w64);
  int d = ldidx(edge, (long long)E + e, w64);
  int p = atomicAdd(&cnt[d], 1);
  colidx[rowptr[d] + p] = s;
}
__global__ void graph_bounds_k(const int* __restrict__ b, int Nn, int G,
                               int* __restrict__ gstart, const int* __restrict__ flags) {
  int w64 = flags[0];
  int g = blockIdx.x * blockDim.x + threadIdx.x;
  if (g > G) return;
  int lo = 0, hi = Nn;
  while (lo < hi) {
    int mid = (lo + hi) >> 1;
    if (ldidx(b, mid, w64) < g) lo = mid + 1; else hi = mid;
  }
  gstart[g] = lo;
}

// x (dual width) -> fp16
__global__ void convert_k(const void* __restrict__ x, unsigned short* __restrict__ xh,
                          long long n, const int* __restrict__ flags) {
  int wf32 = flags[1];
  long long base = ((long long)blockIdx.x * blockDim.x + threadIdx.x) * 4;
  if (base >= n) return;
#pragma unroll
  for (int k = 0; k < 4; k++) xh[base + k] = f2h16(lin(x, base + k, wf32));
}

// fused aggregation: u[i] = hn(i) + sum_{j in nbrs(i)} hn(j)
// hn = APPLY ? relu(v*scale+shift) : v.  LPN lanes per node, 8 fp16 per lane.
template <int LPN, int APPLY>
__global__ void gather_fused_k(const unsigned short* __restrict__ src,
                               const float* __restrict__ scale, const float* __restrict__ shift,
                               const int* __restrict__ rowptr, const int* __restrict__ colidx,
                               unsigned short* __restrict__ u, int Nn) {
  const int F = LPN * 8;
  int gid = blockIdx.x * blockDim.x + threadIdx.x;
  int node = gid / LPN;
  if (node >= Nn) return;
  int fb = (gid % LPN) * 8;
  float sc[8], sh[8];
  if (APPLY) {
#pragma unroll
    for (int k = 0; k < 8; k++) { sc[k] = scale[fb + k]; sh[k] = shift[fb + k]; }
  }
  float acc[8];
  {
    uint4 raw = *(const uint4*)(src + (long long)node * F + fb);
    unsigned int ws[4] = {raw.x, raw.y, raw.z, raw.w};
#pragma unroll
    for (int k = 0; k < 8; k++) {
      float xv = h2f((unsigned short)((ws[k >> 1] >> ((k & 1) * 16)) & 0xffff));
      acc[k] = APPLY ? fmaxf(xv * sc[k] + sh[k], 0.f) : xv;
    }
  }
  int s = rowptr[node], e = rowptr[node + 1];
  for (int j = s; j < e; j++) {
    long long nb = colidx[j];
    uint4 raw = *(const uint4*)(src + nb * F + fb);
    unsigned int ws[4] = {raw.x, raw.y, raw.z, raw.w};
#pragma unroll
    for (int k = 0; k < 8; k++) {
      float xv = h2f((unsigned short)((ws[k >> 1] >> ((k & 1) * 16)) & 0xffff));
      acc[k] += APPLY ? fmaxf(xv * sc[k] + sh[k], 0.f) : xv;
    }
  }
  uint4 o;
  unsigned int wo[4];
#pragma unroll
  for (int p = 0; p < 4; p++)
    wo[p] = (unsigned int)f2h16(acc[2 * p]) | ((unsigned int)f2h16(acc[2 * p + 1]) << 16);
  o.x = wo[0]; o.y = wo[1]; o.z = wo[2]; o.w = wo[3];
  *(uint4*)(u + (long long)node * F + fb) = o;
}

// stage one 128-row A-tile into LDS region R via global_load_lds (width 16).
// LDS dest is linear (base + lane*16); the XOR swizzle is applied to the
// per-lane GLOBAL source chunk instead (inverse of the read-side XOR).
// Region layout: row r occupies bytes [r*2K, (r+1)*2K); chunk i at 16*i holds
// global chunk i^(r&7).
template <int KIN>
__device__ __forceinline__ void stage_tile_lds(
    const unsigned short* __restrict__ A, long long row0, int M,
    unsigned char* R, int tid) {
  const int lane = tid & 63, wave = tid >> 6;
  constexpr int ROWB = 2 * KIN;            // bytes per row (256 or 512)
  constexpr int CHUNKS = ROWB / 16;        // 16B chunks per row (16 or 32)
  constexpr int NISSUE = (128 * ROWB) / (8 * 1024);  // 4 or 8
#pragma unroll
  for (int j = 0; j < NISSUE; j++) {
    int slot = j * 8 + wave;               // which KB of the tile (wave-uniform)
    int baseRow = (slot * 1024) / ROWB;
    int row = baseRow + lane / CHUNKS;
    int ci = lane % CHUNKS;                // chunk slot this lane fills
    int c = ci ^ (row & 7);                // source chunk (inverse swizzle)
    long long rg = row0 + row;
    if (rg >= M) rg = M - 1;
    gload_lds16(A + rg * KIN + c * 8, R + slot * 1024);
  }
}

// =====================================================================
// fused_layer_k: per-layer v = (relu(u@W1+b1))@W2 + b2, + BN column stats.
// Persistent: 256 blocks (1/CU), 512 threads (8 waves), LDS 2x64KB regions.
// Region roles per tile t: Rp = A(t) -> h1(t) -> v-staging -> BN scratch;
// Rq = destination for async-prefetched A(t+1) (global_load_lds, issued after
// bar1; drained by the compiler's vmcnt(0) at bar2).
// Both MFMA stages computed transposed (A-op = W rows, B-op = data rows) so
// each lane's 4 accum values are 4 consecutive cols of one row -> b64 packs.
// =====================================================================
template <int KIN>
__global__ __launch_bounds__(512, 2) void fused_layer_k(
    const unsigned short* __restrict__ A, const unsigned short* __restrict__ W1t,
    const unsigned short* __restrict__ W2t, const float* __restrict__ b1,
    const float* __restrict__ b2, unsigned short* __restrict__ V,
    int M, int ntiles, float* __restrict__ gsum) {
  __shared__ __align__(16) unsigned char lds_raw[131072];
  const int tid = threadIdx.x;
  const int lane = tid & 63, wave = tid >> 6;
  const int l15 = lane & 15, lq = lane >> 4;
  const int wn = wave >> 1, wm = wave & 1;
  const int nb0 = wn * 64, mb0 = wm * 64;
  constexpr int KT1 = KIN / 32;       // stage-1 k-tiles (4 or 8)

  // ---- prologue: stage A(tile blockIdx.x) into region 0 ----
  if ((int)blockIdx.x < ntiles)
    stage_tile_lds<KIN>(A, (long long)blockIdx.x * 128, M, lds_raw, tid);
  __syncthreads();  // compiler drains vmcnt before barrier -> tile resident

  unsigned char* Rp = lds_raw;
  unsigned char* Rq = lds_raw + 65536;
  for (int t = blockIdx.x; t < ntiles; t += 256) {
    long long m0 = (long long)t * 128;
    int tn = t + 256;
    bool hasNext = tn < ntiles;
    // ---- stage 1: h1T[n][m] = relu((u @ W1)^T + b1) ----
    f32x4 acc[4][4] = {};
#pragma unroll
    for (int kt = 0; kt < KT1; kt++) {
      f16x8 wf[4], uf[4];
#pragma unroll
      for (int r = 0; r < 4; r++)
        wf[r] = *(const f16x8*)(W1t + (long long)(nb0 + 16 * r + l15) * KIN + kt * 32 + lq * 8);
#pragma unroll
      for (int c = 0; c < 4; c++) {
        int m = mb0 + 16 * c + l15;
        uf[c] = *(const f16x8*)(Rp + m * (2 * KIN) + 16 * ((kt * 4 + lq) ^ (m & 7)));
      }
#pragma unroll
      for (int r = 0; r < 4; r++)
#pragma unroll
        for (int c = 0; c < 4; c++)
          acc[r][c] = __builtin_amdgcn_mfma_f32_16x16x32_f16(wf[r], uf[c], acc[r][c], 0, 0, 0);
    }
    __syncthreads();  // bar1: all stage-1 reads of Rp done; prev BN reads done
    // async-prefetch A(t+1) -> Rq (issued first; latency hides under epilogue)
    if (hasNext) stage_tile_lds<KIN>(A, (long long)tn * 128, M, Rq, tid);
    // h1 -> Rp (row m, 512B stride, swizzled); bias + relu
#pragma unroll
    for (int r = 0; r < 4; r++) {
      int nbase = nb0 + 16 * r + lq * 4;
      float4 bv = *(const float4*)(b1 + nbase);
#pragma unroll
      for (int c = 0; c < 4; c++) {
        int m = mb0 + 16 * c + l15;
        unsigned int h0 = f2h16(fmaxf(acc[r][c][0] + bv.x, 0.f));
        unsigned int h1v = f2h16(fmaxf(acc[r][c][1] + bv.y, 0.f));
        unsigned int h2v = f2h16(fmaxf(acc[r][c][2] + bv.z, 0.f));
        unsigned int h3 = f2h16(fmaxf(acc[r][c][3] + bv.w, 0.f));
        uint2 pk; pk.x = h0 | (h1v << 16); pk.y = h2v | (h3 << 16);
        int by = m * 512 + 16 * ((nbase >> 3) ^ (m & 7)) + ((nbase & 7) << 1);
        *(uint2*)(Rp + by) = pk;
      }
    }
    __syncthreads();  // bar2: h1 visible; A(t+1) loads drained (vmcnt(0))
    // ---- stage 2: vT[n][m] = (h1 @ W2)^T + b2 ----
    f32x4 acc2[4][4] = {};
#pragma unroll
    for (int kt = 0; kt < 8; kt++) {
      f16x8 wf[4], hf[4];
#pragma unroll
      for (int r = 0; r < 4; r++)
        wf[r] = *(const f16x8*)(W2t + (long long)(nb0 + 16 * r + l15) * 256 + kt * 32 + lq * 8);
#pragma unroll
      for (int c = 0; c < 4; c++) {
        int m = mb0 + 16 * c + l15;
        hf[c] = *(const f16x8*)(Rp + m * 512 + 16 * ((kt * 4 + lq) ^ (m & 7)));
      }
#pragma unroll
      for (int r = 0; r < 4; r++)
#pragma unroll
        for (int c = 0; c < 4; c++)
          acc2[r][c] = __builtin_amdgcn_mfma_f32_16x16x32_f16(wf[r], hf[c], acc2[r][c], 0, 0, 0);
    }
    __syncthreads();  // bar3: all stage-2 reads of h1 done
    // v -> Rp ([m][n], swizzled); bias, no relu
#pragma unroll
    for (int r = 0; r < 4; r++) {
      int nbase = nb0 + 16 * r + lq * 4;
      float4 bv = *(const float4*)(b2 + nbase);
#pragma unroll
      for (int c = 0; c < 4; c++) {
        int m = mb0 + 16 * c + l15;
        unsigned int h0 = f2h16(acc2[r][c][0] + bv.x);
        unsigned int h1v = f2h16(acc2[r][c][1] + bv.y);
        unsigned int h2v = f2h16(acc2[r][c][2] + bv.z);
        unsigned int h3 = f2h16(acc2[r][c][3] + bv.w);
        uint2 pk; pk.x = h0 | (h1v << 16); pk.y = h2v | (h3 << 16);
        int by = m * 512 + 16 * ((nbase >> 3) ^ (m & 7)) + ((nbase & 7) << 1);
        *(uint2*)(Rp + by) = pk;
      }
    }
    __syncthreads();  // bar4: v tile complete
    // coalesced store + BN partials
    const int c32 = tid & 31, rg = tid >> 5;
    float s8[8] = {}, q8[8] = {};
#pragma unroll
    for (int k = 0; k < 8; k++) {
      int m = rg * 8 + k;
      uint4 vw = *(const uint4*)(Rp + m * 512 + 16 * (c32 ^ (m & 7)));
      long long grow = m0 + m;
      if (grow < M) {
        *(uint4*)(V + grow * 256 + c32 * 8) = vw;
        unsigned int ws[4] = {vw.x, vw.y, vw.z, vw.w};
#pragma unroll
        for (int kk = 0; kk < 8; kk++) {
          float xv = h2f((unsigned short)((ws[kk >> 1] >> ((kk & 1) * 16)) & 0xffff));
          s8[kk] += xv; q8[kk] += xv * xv;
        }
      }
    }
    __syncthreads();  // bar5: v reads done; Rp reusable as scratch
    float* shf = (float*)Rp;  // [256][17] sums + [256][17] sumsq = 34816 B
#pragma unroll
    for (int kk = 0; kk < 8; kk++) {
      int col = c32 * 8 + kk;
      shf[col * 17 + rg] = s8[kk];
      shf[4352 + col * 17 + rg] = q8[kk];
    }
    __syncthreads();  // bar6
    if (tid < 256) {
      float tot = 0.f;
#pragma unroll
      for (int g = 0; g < 16; g++) tot += shf[tid * 17 + g];
      atomicAdd(&gsum[tid], tot);
    } else {
      int col = tid - 256; float tot = 0.f;
#pragma unroll
      for (int g = 0; g < 16; g++) tot += shf[4352 + col * 17 + g];
      atomicAdd(&gsum[256 + col], tot);
    }
    unsigned char* tmp = Rp; Rp = Rq; Rq = tmp;  // Rq(A(t+1)) becomes Rp
  }
}

// MFMA fp16 GEMM (predictor only). Tile 128x128, BK=32, 4 waves.
#define SA 40    // padded A/B staging stride (fp16)
#define SP 136   // padded C-tile stride (fp16)
__global__ __launch_bounds__(256) void gemm_k(
    const unsigned short* __restrict__ A, const unsigned short* __restrict__ Bt,
    const float* __restrict__ bias, unsigned short* __restrict__ C,
    int M, int K, int relu, float* __restrict__ gsum) {
  __shared__ __align__(16) unsigned short smem[128 * SP];
  unsigned short* As = smem;
  unsigned short* Bs = smem + 128 * SA;
  int m0 = blockIdx.x * 128, n0 = blockIdx.y * 128;
  int tid = threadIdx.x;
  int wave = tid >> 6, lane = tid & 63;
  int wm = (wave >> 1) * 64, wnn = (wave & 1) * 64;
  int lrow = lane & 15, lqq = lane >> 4;
  f32x4 acc[4][4] = {};
  int ktiles = K >> 5;
  int srow = tid >> 2;
  int ch8 = (tid & 3) << 3;
  int rowA0 = m0 + srow;      rowA0 = rowA0 < M ? rowA0 : M - 1;
  int rowA1 = m0 + srow + 64; rowA1 = rowA1 < M ? rowA1 : M - 1;
  const unsigned short* pa0 = A + (long long)rowA0 * K + ch8;
  const unsigned short* pa1 = A + (long long)rowA1 * K + ch8;
  const unsigned short* pq0 = Bt + (long long)(n0 + srow) * K + ch8;
  const unsigned short* pq1 = Bt + (long long)(n0 + srow + 64) * K + ch8;
  uint4 va0 = *(const uint4*)pa0, va1 = *(const uint4*)pa1;
  uint4 vb0 = *(const uint4*)pq0, vb1 = *(const uint4*)pq1;
  int lo0 = srow * SA + ch8, lo1 = (srow + 64) * SA + ch8;
  for (int kt = 0; kt < ktiles; ++kt) {
    __syncthreads();
    *(uint4*)(As + lo0) = va0;
    *(uint4*)(As + lo1) = va1;
    *(uint4*)(Bs + lo0) = vb0;
    *(uint4*)(Bs + lo1) = vb1;
    __syncthreads();
    f16x8 af[4], bf[4];
#pragma unroll
    for (int r = 0; r < 4; r++)
      af[r] = *(const f16x8*)(As + (wm + 16 * r + lrow) * SA + lqq * 8);
#pragma unroll
    for (int c = 0; c < 4; c++)
      bf[c] = *(const f16x8*)(Bs + (wnn + 16 * c + lrow) * SA + lqq * 8);
    if (kt + 1 < ktiles) {
      int kb = (kt + 1) << 5;
      va0 = *(const uint4*)(pa0 + kb); va1 = *(const uint4*)(pa1 + kb);
      vb0 = *(const uint4*)(pq0 + kb); vb1 = *(const uint4*)(pq1 + kb);
    }
#pragma unroll
    for (int r = 0; r < 4; r++)
#pragma unroll
      for (int c = 0; c < 4; c++)
        acc[r][c] = __builtin_amdgcn_mfma_f32_16x16x32_f16(af[r], bf[c], acc[r][c], 0, 0, 0);
  }
  __syncthreads();
  unsigned short* Ct = smem;
#pragma unroll
  for (int c = 0; c < 4; c++) {
    int col = wnn + 16 * c + lrow;
    float bv = bias[n0 + col];
#pragma unroll
    for (int r = 0; r < 4; r++) {
      int rbase = wm + 16 * r + lqq * 4;
#pragma unroll
      for (int i = 0; i < 4; i++) {
        float v = acc[r][c][i] + bv;
        if (relu) v = fmaxf(v, 0.f);
        Ct[(rbase + i) * SP + col] = f2h16(v);
      }
    }
  }
  __syncthreads();
  int c16 = tid & 15, g = tid >> 4;
  float s8[8] = {}, q8[8] = {};
  bool dostats = (gsum != nullptr);
#pragma unroll
  for (int i = 0; i < 8; i++) {
    int row = g + i * 16;
    int grow = m0 + row;
    uint4 vw = *(const uint4*)(Ct + row * SP + c16 * 8);
    if (grow < M) {
      *(uint4*)(C + (long long)grow * 256 + n0 + c16 * 8) = vw;
      if (dostats) {
        unsigned int ws[4] = {vw.x, vw.y, vw.z, vw.w};
#pragma unroll
        for (int k = 0; k < 8; k++) {
          float xv = h2f((unsigned short)((ws[k >> 1] >> ((k & 1) * 16)) & 0xffff));
          s8[k] += xv; q8[k] += xv * xv;
        }
      }
    }
  }
  if (dostats) {
    float* shf = (float*)smem;
    __syncthreads();
#pragma unroll
    for (int k = 0; k < 8; k++) shf[(c16 * 8 + k) * 17 + g] = s8[k];
    __syncthreads();
    if (tid < 128) {
      float t = 0.f;
#pragma unroll
      for (int gg = 0; gg < 16; gg++) t += shf[tid * 17 + gg];
      atomicAdd(&gsum[n0 + tid], t);
    }
    __syncthreads();
#pragma unroll
    for (int k = 0; k < 8; k++) shf[(c16 * 8 + k) * 17 + g] = q8[k];
    __syncthreads();
    if (tid < 128) {
      float t = 0.f;
#pragma unroll
      for (int gg = 0; gg < 16; gg++) t += shf[tid * 17 + gg];
      atomicAdd(&gsum[256 + n0 + tid], t);
    }
  }
}

__global__ void bn_finalize_k(const float* __restrict__ gsum,
                              const float* __restrict__ pg, const float* __restrict__ pb,
                              int Nn, float* __restrict__ scale, float* __restrict__ shift) {
  int f = threadIdx.x;
  float inv = 1.f / (float)Nn;
  float mean = gsum[f] * inv;
  float var = fmaxf(gsum[256 + f] * inv - mean * mean, 0.f);
  float sc = pg[f] * rsqrtf(var + 1e-5f);
  scale[f] = sc;
  shift[f] = pb[f] - mean * sc;
}

// fused pool: mean over graph rows of relu(v*sc+sh)
__global__ void pool_fused_k(const unsigned short* __restrict__ v, const float* __restrict__ scale,
                             const float* __restrict__ shift, const int* __restrict__ gstart,
                             unsigned short* __restrict__ gout) {
  int g = blockIdx.x, f = threadIdx.x;
  int s = gstart[g], e = gstart[g + 1];
  float sc = scale[f], sh = shift[f];
  float acc = 0.f;
  for (int r = s; r < e; r++) acc += fmaxf(h2f(v[(long long)r * 256 + f]) * sc + sh, 0.f);
  gout[(long long)g * 256 + f] = f2h16(acc / fmaxf((float)(e - s), 1.f));
}
__global__ void pred2_k(const unsigned short* __restrict__ p1, const void* __restrict__ Wp2,
                        const void* __restrict__ bp2, void* __restrict__ out, int G,
                        const int* __restrict__ flags) {
  int wf32 = flags[1];
  int idx = blockIdx.x * blockDim.x + threadIdx.x;
  if (idx >= G * 12) return;
  int g = idx / 12, t = idx - g * 12;
  float acc = lin(bp2, t, wf32);
  const unsigned short* row = p1 + (long long)g * 256;
  for (int k = 0; k < 256; k++) acc += h2f(row[k]) * lin(Wp2, k * 12 + t, wf32);
  if (wf32) ((float*)out)[idx] = acc;
  else      ((unsigned short*)out)[idx] = f2b(acc);
}

extern "C" void kernel_launch(void* const* d_in, const int* in_sizes, int n_in,
                              void* d_out, int out_size, void* d_ws, size_t ws_size,
                              hipStream_t stream) {
  int wb = -1;
  for (int i = 3; i + 15 < n_in; i++) {
    if (in_sizes[i] == 32768 && in_sizes[i + 1] == 256 && in_sizes[i + 2] == 65536 &&
        in_sizes[i + 3] == 256 && in_sizes[i + 4] == 256 && in_sizes[i + 5] == 256 &&
        in_sizes[i + 6] == 262144) { wb = i; break; }
  }
  if (wb < 0) wb = (n_in >= 20) ? 4 : 3;

  const void* x      = d_in[0];
  const int*  edge   = (const int*)d_in[1];
  const int*  batch  = (const int*)d_in[2];
  const void* W1_0   = d_in[wb + 0];
  const void* b1_0   = d_in[wb + 1];
  const void* W2_0   = d_in[wb + 2];
  const void* b2_0   = d_in[wb + 3];
  const void* gamma0 = d_in[wb + 4];
  const void* beta0  = d_in[wb + 5];
  const void* W1s    = d_in[wb + 6];
  const void* b1s    = d_in[wb + 7];
  const void* W2s    = d_in[wb + 8];
  const void* b2s    = d_in[wb + 9];
  const void* gammas = d_in[wb + 10];
  const void* betas  = d_in[wb + 11];
  const void* Wp1    = d_in[wb + 12];
  const void* bp1    = d_in[wb + 13];
  const void* Wp2    = d_in[wb + 14];
  const void* bp2    = d_in[wb + 15];

  const int N = in_sizes[0] / 128;
  const int E = in_sizes[1] / 2;
  const int G = out_size / 12;
  const int H = 256;

  char* w = (char*)d_ws;
  size_t off = 0;
  auto alloc = [&](size_t bytes) -> char* {
    char* p = w + off;
    off += (bytes + 255) & ~(size_t)255;
    return p;
  };
  unsigned short* bufX  = (unsigned short*)alloc((size_t)N * H * 2);
  unsigned short* bufY  = (unsigned short*)alloc((size_t)N * H * 2);  // xh parks here first
  unsigned short* w1_0t = (unsigned short*)alloc((size_t)128 * 256 * 2);
  unsigned short* w2_0t = (unsigned short*)alloc((size_t)256 * 256 * 2);
  unsigned short* w1st  = (unsigned short*)alloc((size_t)4 * 256 * 256 * 2);
  unsigned short* w2st  = (unsigned short*)alloc((size_t)4 * 256 * 256 * 2);
  unsigned short* wp1t  = (unsigned short*)alloc((size_t)256 * 256 * 2);
  int*   rowptr   = (int*)alloc((size_t)(N + 1) * 4);
  int*   cnt      = (int*)alloc((size_t)N * 4);
  int*   colidx   = (int*)alloc((size_t)E * 4);
  int*   partials = (int*)alloc(1024 * 4);
  float* gsum     = (float*)alloc(512 * 4);
  float* bnscale  = (float*)alloc(256 * 4);
  float* bnshift  = (float*)alloc(256 * 4);
  float* pg       = (float*)alloc(256 * 4);
  float* pb       = (float*)alloc(256 * 4);
  float* pb1      = (float*)alloc(256 * 4);
  float* pb2      = (float*)alloc(256 * 4);
  int*   gstart   = (int*)alloc((size_t)(G + 1) * 4);
  int*   flags    = (int*)alloc(256);
  unsigned short* gpool = (unsigned short*)alloc((size_t)G * H * 2);
  unsigned short* p1    = (unsigned short*)alloc((size_t)G * H * 2);
  (void)ws_size; (void)n_in;

  detect_k<<<1, 64, 0, stream>>>(edge, (const unsigned short*)x, flags);

  // x -> fp16 into bufY (dead once layer-0 fused kernel overwrites bufY)
  convert_k<<<(int)(((long long)N * 128 / 4 + 255) / 256), 256, 0, stream>>>(
      x, bufY, (long long)N * 128, flags);

  dim3 tb(32, 8);
  auto transpose = [&](const void* src, long long eoff, unsigned short* dst, int R, int C) {
    transpose_off_k<<<dim3((C + 31) / 32, (R + 31) / 32), tb, 0, stream>>>(src, eoff, dst, R, C, flags);
  };
  transpose(W1_0, 0, w1_0t, 128, 256);
  transpose(W2_0, 0, w2_0t, 256, 256);
  for (int i = 0; i < 4; i++) {
    transpose(W1s, (long long)i * 65536, w1st + i * 65536, 256, 256);
    transpose(W2s, (long long)i * 65536, w2st + i * 65536, 256, 256);
  }
  transpose(Wp1, 0, wp1t, 256, 256);

  // CSR
  zero_i32_k<<<(N + 255) / 256, 256, 0, stream>>>(cnt, N);
  hist_k<<<(E + 255) / 256, 256, 0, stream>>>(edge, E, cnt, flags);
  int NB = (N + SCAN_CHUNK - 1) / SCAN_CHUNK;
  scan1_k<<<NB, 256, 0, stream>>>(cnt, rowptr, partials, N);
  scan2_k<<<1, 256, 0, stream>>>(partials, NB);
  scan3_k<<<NB, 256, 0, stream>>>(rowptr, partials, N, E);
  zero_i32_k<<<(N + 255) / 256, 256, 0, stream>>>(cnt, N);
  fill_k<<<(E + 255) / 256, 256, 0, stream>>>(edge, E, rowptr, cnt, colidx, flags);
  graph_bounds_k<<<(G + 1 + 255) / 256, 256, 0, stream>>>(batch, N, G, gstart, flags);

  const int ntiles = (N + 127) / 128;
  auto fused = [&](const unsigned short* Au, const unsigned short* w1, const unsigned short* w2,
                   unsigned short* Vv, int K) {
    if (K == 128)
      fused_layer_k<128><<<256, 512, 0, stream>>>(Au, w1, w2, pb1, pb2, Vv, N, ntiles, gsum);
    else
      fused_layer_k<256><<<256, 512, 0, stream>>>(Au, w1, w2, pb1, pb2, Vv, N, ntiles, gsum);
  };

  // ---- layer 0 ----
  prep_k<<<1, 256, 0, stream>>>(b1_0, b2_0, gamma0, beta0, 0, pb1, pb2, pg, pb, gsum, flags);
  gather_fused_k<16, 0><<<(N * 16 + 255) / 256, 256, 0, stream>>>(
      bufY, bnscale, bnshift, rowptr, colidx, bufX, N);
  fused(bufX, w1_0t, w2_0t, bufY, 128);   // v0 + fused BN stats -> bufY
  bn_finalize_k<<<1, 256, 0, stream>>>(gsum, pg, pb, N, bnscale, bnshift);
  unsigned short* cur = bufY;  // pre-BN v0
  unsigned short* oth = bufX;
  // ---- layers 1..4 ----
  for (int i = 0; i < 4; i++) {
    prep_k<<<1, 256, 0, stream>>>(b1s, b2s, gammas, betas, i * 256, pb1, pb2, pg, pb, gsum, flags);
    gather_fused_k<32, 1><<<(N * 32 + 255) / 256, 256, 0, stream>>>(
        cur, bnscale, bnshift, rowptr, colidx, oth, N);
    fused(oth, w1st + i * 65536, w2st + i * 65536, cur, 256);  // v_i + BN stats -> cur
    bn_finalize_k<<<1, 256, 0, stream>>>(gsum, pg, pb, N, bnscale, bnshift);
  }

  // ---- pool + predictor ----
  copy256_k<<<1, 256, 0, stream>>>(bp1, 0, pb1, flags);
  pool_fused_k<<<G, 256, 0, stream>>>(cur, bnscale, bnshift, gstart, gpool);
  gemm_k<<<dim3((G + 127) / 128, 2), 256, 0, stream>>>(gpool, wp1t, pb1, p1, G, 256, 1, nullptr);
  pred2_k<<<(G * 12 + 255) / 256, 256, 0, stream>>>(p1, Wp2, bp2, d_out, G, flags);
}

// Round 3
// 964.886 us; speedup vs baseline: 1.3747x; 1.1745x over previous
//
#include <hip/hip_runtime.h>

// GINModel on MI355X (gfx950). Round 9:
//  - fused_layer_k round-8 post-mortem: FETCH identical across K=128/K=256
//    dispatches -> observed HBM traffic is NOT input traffic; it's scratch.
//    The fully-unrolled kt loops let the compiler hoist 32 global weight-
//    fragment loads (128 VGPRs in flight) and spill the accumulators.
//    Fix: #pragma unroll 1 on both MFMA kt loops (per-iteration pressure
//    ~110 VGPR, loop-carried acc stays in registers).
//  - everything else unchanged from round 8.
// fp16 internal storage, fp32 accumulation, dual-width input hardening.

typedef __attribute__((ext_vector_type(4))) float f32x4;
typedef __attribute__((ext_vector_type(8))) _Float16 f16x8;

__device__ __forceinline__ float h2f(unsigned short u) {
  _Float16 h; __builtin_memcpy(&h, &u, 2); return (float)h;
}
__device__ __forceinline__ unsigned short f2h16(float f) {
  _Float16 h = (_Float16)f; unsigned short u; __builtin_memcpy(&u, &h, 2); return u;
}
__device__ __forceinline__ unsigned short f2b(float f) {  // fp32 -> bf16 RNE
  union { float f; unsigned int i; } c; c.f = f;
  unsigned int x = c.i;
  return (unsigned short)((x + 0x7fffu + ((x >> 16) & 1u)) >> 16);
}
__device__ __forceinline__ float lin(const void* p, long long i, int wf32) {
  if (wf32) return ((const float*)p)[i];
  union { unsigned int i; float f; } c;
  c.i = ((unsigned int)((const unsigned short*)p)[i]) << 16;
  return c.f;
}
__device__ __forceinline__ int ldidx(const int* p, long long i, int w64) {
  return w64 ? p[2 * i] : p[i];
}

// async global->LDS, 16B per lane; LDS dest = wave-uniform base + lane*16
__device__ __forceinline__ void gload_lds16(const void* g, void* l) {
  __builtin_amdgcn_global_load_lds(
      (const __attribute__((address_space(1))) unsigned int*)g,
      (__attribute__((address_space(3))) unsigned int*)l, 16, 0, 0);
}

// flags[0]=w64 (int64 indices), flags[1]=wf32 (fp32 floats)
__global__ void detect_k(const int* __restrict__ edge, const unsigned short* __restrict__ xa,
                         int* __restrict__ flags) {
  if (threadIdx.x != 0 || blockIdx.x != 0) return;
  int nzOdd = 0;
  for (int t = 0; t < 256; t++) if (edge[2 * t + 1] != 0) nzOdd++;
  flags[0] = (nzOdd == 0) ? 1 : 0;
  int plaus = 0;
  for (int t = 0; t < 64; t++) {
    unsigned short w = xa[2 * t];
    int e = (w >> 7) & 0xFF;
    if (w == 0 || (e >= 0x70 && e <= 0x85)) plaus++;
  }
  flags[1] = (plaus < 32) ? 1 : 0;
}

__global__ void zero_i32_k(int* __restrict__ p, int n) {
  int i = blockIdx.x * blockDim.x + threadIdx.x;
  if (i < n) p[i] = 0;
}

// per-layer prep: slice 4x256 params to fp32 + zero BN accumulators (512 f32)
__global__ void prep_k(const void* __restrict__ b1, const void* __restrict__ b2,
                       const void* __restrict__ gm, const void* __restrict__ bt, int eoff,
                       float* __restrict__ pb1, float* __restrict__ pb2,
                       float* __restrict__ pg, float* __restrict__ pb,
                       float* __restrict__ gsum, const int* __restrict__ flags) {
  int wf32 = flags[1], t = threadIdx.x;
  pb1[t] = lin(b1, (long long)eoff + t, wf32);
  pb2[t] = lin(b2, (long long)eoff + t, wf32);
  pg[t]  = lin(gm, (long long)eoff + t, wf32);
  pb[t]  = lin(bt, (long long)eoff + t, wf32);
  gsum[t] = 0.f; gsum[256 + t] = 0.f;
}
__global__ void copy256_k(const void* __restrict__ src, int eoff, float* __restrict__ dst,
                          const int* __restrict__ flags) {
  dst[threadIdx.x] = lin(src, (long long)eoff + threadIdx.x, flags[1]);
}

// input (R x C at element offset, dual width) -> fp16 transposed (C x R)
__global__ void transpose_off_k(const void* __restrict__ src, long long eoff,
                                unsigned short* __restrict__ dst, int R, int C,
                                const int* __restrict__ flags) {
  int wf32 = flags[1];
  __shared__ unsigned short t[32][33];
  int bx = blockIdx.x * 32, by = blockIdx.y * 32;
  int x = bx + threadIdx.x;
  for (int i = 0; i < 32; i += 8) {
    int y = by + threadIdx.y + i;
    if (y < R && x < C)
      t[threadIdx.y + i][threadIdx.x] = f2h16(lin(src, eoff + (long long)y * C + x, wf32));
  }
  __syncthreads();
  int x2 = by + threadIdx.x;
  for (int i = 0; i < 32; i += 8) {
    int y = bx + threadIdx.y + i;
    if (y < C && x2 < R) dst[(long long)y * R + x2] = t[threadIdx.x][threadIdx.y + i];
  }
}

// ---------------- CSR ----------------
__global__ void hist_k(const int* __restrict__ edge, int E, int* __restrict__ cnt,
                       const int* __restrict__ flags) {
  int w64 = flags[0];
  int e = blockIdx.x * blockDim.x + threadIdx.x;
  if (e < E) atomicAdd(&cnt[ldidx(edge, (long long)E + e, w64)], 1);
}
#define SCAN_CHUNK 1024
__global__ void scan1_k(const int* __restrict__ in, int* __restrict__ out,
                        int* __restrict__ partials, int n) {
  __shared__ int sh[256];
  int tid = threadIdx.x;
  int base = blockIdx.x * SCAN_CHUNK + tid * 4;
  int v[4]; int tsum = 0;
#pragma unroll
  for (int i = 0; i < 4; i++) { v[i] = (base + i < n) ? in[base + i] : 0; tsum += v[i]; }
  sh[tid] = tsum; __syncthreads();
  for (int off = 1; off < 256; off <<= 1) {
    int t = (tid >= off) ? sh[tid - off] : 0;
    __syncthreads();
    sh[tid] += t;
    __syncthreads();
  }
  int run = sh[tid] - tsum;
#pragma unroll
  for (int i = 0; i < 4; i++) { if (base + i < n) out[base + i] = run; run += v[i]; }
  if (tid == 255) partials[blockIdx.x] = sh[255];
}
__global__ void scan2_k(int* partials, int B) {
  __shared__ int sh[256];
  int tid = threadIdx.x;
  int orig = (tid < B) ? partials[tid] : 0;
  sh[tid] = orig; __syncthreads();
  for (int off = 1; off < 256; off <<= 1) {
    int t = (tid >= off) ? sh[tid - off] : 0;
    __syncthreads();
    sh[tid] += t;
    __syncthreads();
  }
  if (tid < B) partials[tid] = sh[tid] - orig;
}
__global__ void scan3_k(int* __restrict__ out, const int* __restrict__ partials,
                        int n, int total) {
  int base = blockIdx.x * SCAN_CHUNK + threadIdx.x * 4;
  int add = partials[blockIdx.x];
#pragma unroll
  for (int i = 0; i < 4; i++) { if (base + i < n) out[base + i] += add; }
  if (blockIdx.x == 0 && threadIdx.x == 0) out[n] = total;
}
__global__ void fill_k(const int* __restrict__ edge, int E, const int* __restrict__ rowptr,
                       int* __restrict__ cnt, int* __restrict__ colidx,
                       const int* __restrict__ flags) {
  int w64 = flags[0];
  int e = blockIdx.x * blockDim.x + threadIdx.x;
  if (e >= E) return;
  int s = ldidx(edge, e, w64);
  int d = ldidx(edge, (long long)E + e, w64);
  int p = atomicAdd(&cnt[d], 1);
  colidx[rowptr[d] + p] = s;
}
__global__ void graph_bounds_k(const int* __restrict__ b, int Nn, int G,
                               int* __restrict__ gstart, const int* __restrict__ flags) {
  int w64 = flags[0];
  int g = blockIdx.x * blockDim.x + threadIdx.x;
  if (g > G) return;
  int lo = 0, hi = Nn;
  while (lo < hi) {
    int mid = (lo + hi) >> 1;
    if (ldidx(b, mid, w64) < g) lo = mid + 1; else hi = mid;
  }
  gstart[g] = lo;
}

// x (dual width) -> fp16
__global__ void convert_k(const void* __restrict__ x, unsigned short* __restrict__ xh,
                          long long n, const int* __restrict__ flags) {
  int wf32 = flags[1];
  long long base = ((long long)blockIdx.x * blockDim.x + threadIdx.x) * 4;
  if (base >= n) return;
#pragma unroll
  for (int k = 0; k < 4; k++) xh[base + k] = f2h16(lin(x, base + k, wf32));
}

// fused aggregation: u[i] = hn(i) + sum_{j in nbrs(i)} hn(j)
// hn = APPLY ? relu(v*scale+shift) : v.  LPN lanes per node, 8 fp16 per lane.
template <int LPN, int APPLY>
__global__ void gather_fused_k(const unsigned short* __restrict__ src,
                               const float* __restrict__ scale, const float* __restrict__ shift,
                               const int* __restrict__ rowptr, const int* __restrict__ colidx,
                               unsigned short* __restrict__ u, int Nn) {
  const int F = LPN * 8;
  int gid = blockIdx.x * blockDim.x + threadIdx.x;
  int node = gid / LPN;
  if (node >= Nn) return;
  int fb = (gid % LPN) * 8;
  float sc[8], sh[8];
  if (APPLY) {
#pragma unroll
    for (int k = 0; k < 8; k++) { sc[k] = scale[fb + k]; sh[k] = shift[fb + k]; }
  }
  float acc[8];
  {
    uint4 raw = *(const uint4*)(src + (long long)node * F + fb);
    unsigned int ws[4] = {raw.x, raw.y, raw.z, raw.w};
#pragma unroll
    for (int k = 0; k < 8; k++) {
      float xv = h2f((unsigned short)((ws[k >> 1] >> ((k & 1) * 16)) & 0xffff));
      acc[k] = APPLY ? fmaxf(xv * sc[k] + sh[k], 0.f) : xv;
    }
  }
  int s = rowptr[node], e = rowptr[node + 1];
  for (int j = s; j < e; j++) {
    long long nb = colidx[j];
    uint4 raw = *(const uint4*)(src + nb * F + fb);
    unsigned int ws[4] = {raw.x, raw.y, raw.z, raw.w};
#pragma unroll
    for (int k = 0; k < 8; k++) {
      float xv = h2f((unsigned short)((ws[k >> 1] >> ((k & 1) * 16)) & 0xffff));
      acc[k] += APPLY ? fmaxf(xv * sc[k] + sh[k], 0.f) : xv;
    }
  }
  uint4 o;
  unsigned int wo[4];
#pragma unroll
  for (int p = 0; p < 4; p++)
    wo[p] = (unsigned int)f2h16(acc[2 * p]) | ((unsigned int)f2h16(acc[2 * p + 1]) << 16);
  o.x = wo[0]; o.y = wo[1]; o.z = wo[2]; o.w = wo[3];
  *(uint4*)(u + (long long)node * F + fb) = o;
}

// stage one 128-row A-tile into LDS region R via global_load_lds (width 16).
// LDS dest is linear (base + lane*16); the XOR swizzle is applied to the
// per-lane GLOBAL source chunk instead (inverse of the read-side XOR).
template <int KIN>
__device__ __forceinline__ void stage_tile_lds(
    const unsigned short* __restrict__ A, long long row0, int M,
    unsigned char* R, int tid) {
  const int lane = tid & 63, wave = tid >> 6;
  constexpr int ROWB = 2 * KIN;            // bytes per row (256 or 512)
  constexpr int CHUNKS = ROWB / 16;        // 16B chunks per row (16 or 32)
  constexpr int NISSUE = (128 * ROWB) / (8 * 1024);  // 4 or 8
#pragma unroll
  for (int j = 0; j < NISSUE; j++) {
    int slot = j * 8 + wave;               // which KB of the tile (wave-uniform)
    int baseRow = (slot * 1024) / ROWB;
    int row = baseRow + lane / CHUNKS;
    int ci = lane % CHUNKS;                // chunk slot this lane fills
    int c = ci ^ (row & 7);                // source chunk (inverse swizzle)
    long long rg = row0 + row;
    if (rg >= M) rg = M - 1;
    gload_lds16(A + rg * KIN + c * 8, R + slot * 1024);
  }
}

// =====================================================================
// fused_layer_k: per-layer v = (relu(u@W1+b1))@W2 + b2, + BN column stats.
// Persistent: 256 blocks (1/CU), 512 threads (8 waves), LDS 2x64KB regions.
// Region roles per tile t: Rp = A(t) -> h1(t) -> v-staging -> BN scratch;
// Rq = destination for async-prefetched A(t+1).
// kt loops are unroll-1: per-iteration register demand ~110 VGPR so the
// loop-carried accumulators stay in registers (round-8's full unroll hoisted
// 32 global weight loads and spilled acc to scratch -> 130MB HBM thrash).
// =====================================================================
template <int KIN>
__global__ __launch_bounds__(512, 2) void fused_layer_k(
    const unsigned short* __restrict__ A, const unsigned short* __restrict__ W1t,
    const unsigned short* __restrict__ W2t, const float* __restrict__ b1,
    const float* __restrict__ b2, unsigned short* __restrict__ V,
    int M, int ntiles, float* __restrict__ gsum) {
  __shared__ __align__(16) unsigned char lds_raw[131072];
  const int tid = threadIdx.x;
  const int lane = tid & 63, wave = tid >> 6;
  const int l15 = lane & 15, lq = lane >> 4;
  const int wn = wave >> 1, wm = wave & 1;
  const int nb0 = wn * 64, mb0 = wm * 64;
  constexpr int KT1 = KIN / 32;       // stage-1 k-tiles (4 or 8)

  // ---- prologue: stage A(tile blockIdx.x) into region 0 ----
  if ((int)blockIdx.x < ntiles)
    stage_tile_lds<KIN>(A, (long long)blockIdx.x * 128, M, lds_raw, tid);
  __syncthreads();  // compiler drains vmcnt before barrier -> tile resident

  unsigned char* Rp = lds_raw;
  unsigned char* Rq = lds_raw + 65536;
  for (int t = blockIdx.x; t < ntiles; t += 256) {
    long long m0 = (long long)t * 128;
    int tn = t + 256;
    bool hasNext = tn < ntiles;
    // ---- stage 1: h1T[n][m] = relu((u @ W1)^T + b1) ----
    f32x4 acc[4][4] = {};
#pragma unroll 1
    for (int kt = 0; kt < KT1; kt++) {
      f16x8 wf[4], uf[4];
#pragma unroll
      for (int r = 0; r < 4; r++)
        wf[r] = *(const f16x8*)(W1t + (long long)(nb0 + 16 * r + l15) * KIN + kt * 32 + lq * 8);
#pragma unroll
      for (int c = 0; c < 4; c++) {
        int m = mb0 + 16 * c + l15;
        uf[c] = *(const f16x8*)(Rp + m * (2 * KIN) + 16 * ((kt * 4 + lq) ^ (m & 7)));
      }
#pragma unroll
      for (int r = 0; r < 4; r++)
#pragma unroll
        for (int c = 0; c < 4; c++)
          acc[r][c] = __builtin_amdgcn_mfma_f32_16x16x32_f16(wf[r], uf[c], acc[r][c], 0, 0, 0);
    }
    __syncthreads();  // bar1: all stage-1 reads of Rp done; prev BN reads done
    // async-prefetch A(t+1) -> Rq (issued first; latency hides under epilogue)
    if (hasNext) stage_tile_lds<KIN>(A, (long long)tn * 128, M, Rq, tid);
    // h1 -> Rp (row m, 512B stride, swizzled); bias + relu
#pragma unroll
    for (int r = 0; r < 4; r++) {
      int nbase = nb0 + 16 * r + lq * 4;
      float4 bv = *(const float4*)(b1 + nbase);
#pragma unroll
      for (int c = 0; c < 4; c++) {
        int m = mb0 + 16 * c + l15;
        unsigned int h0 = f2h16(fmaxf(acc[r][c][0] + bv.x, 0.f));
        unsigned int h1v = f2h16(fmaxf(acc[r][c][1] + bv.y, 0.f));
        unsigned int h2v = f2h16(fmaxf(acc[r][c][2] + bv.z, 0.f));
        unsigned int h3 = f2h16(fmaxf(acc[r][c][3] + bv.w, 0.f));
        uint2 pk; pk.x = h0 | (h1v << 16); pk.y = h2v | (h3 << 16);
        int by = m * 512 + 16 * ((nbase >> 3) ^ (m & 7)) + ((nbase & 7) << 1);
        *(uint2*)(Rp + by) = pk;
      }
    }
    __syncthreads();  // bar2: h1 visible; A(t+1) loads drained (vmcnt(0))
    // ---- stage 2: vT[n][m] = (h1 @ W2)^T + b2 ----
    f32x4 acc2[4][4] = {};
#pragma unroll 1
    for (int kt = 0; kt < 8; kt++) {
      f16x8 wf[4], hf[4];
#pragma unroll
      for (int r = 0; r < 4; r++)
        wf[r] = *(const f16x8*)(W2t + (long long)(nb0 + 16 * r + l15) * 256 + kt * 32 + lq * 8);
#pragma unroll
      for (int c = 0; c < 4; c++) {
        int m = mb0 + 16 * c + l15;
        hf[c] = *(const f16x8*)(Rp + m * 512 + 16 * ((kt * 4 + lq) ^ (m & 7)));
      }
#pragma unroll
      for (int r = 0; r < 4; r++)
#pragma unroll
        for (int c = 0; c < 4; c++)
          acc2[r][c] = __builtin_amdgcn_mfma_f32_16x16x32_f16(wf[r], hf[c], acc2[r][c], 0, 0, 0);
    }
    __syncthreads();  // bar3: all stage-2 reads of h1 done
    // v -> Rp ([m][n], swizzled); bias, no relu
#pragma unroll
    for (int r = 0; r < 4; r++) {
      int nbase = nb0 + 16 * r + lq * 4;
      float4 bv = *(const float4*)(b2 + nbase);
#pragma unroll
      for (int c = 0; c < 4; c++) {
        int m = mb0 + 16 * c + l15;
        unsigned int h0 = f2h16(acc2[r][c][0] + bv.x);
        unsigned int h1v = f2h16(acc2[r][c][1] + bv.y);
        unsigned int h2v = f2h16(acc2[r][c][2] + bv.z);
        unsigned int h3 = f2h16(acc2[r][c][3] + bv.w);
        uint2 pk; pk.x = h0 | (h1v << 16); pk.y = h2v | (h3 << 16);
        int by = m * 512 + 16 * ((nbase >> 3) ^ (m & 7)) + ((nbase & 7) << 1);
        *(uint2*)(Rp + by) = pk;
      }
    }
    __syncthreads();  // bar4: v tile complete
    // coalesced store + BN partials
    const int c32 = tid & 31, rg = tid >> 5;
    float s8[8] = {}, q8[8] = {};
#pragma unroll
    for (int k = 0; k < 8; k++) {
      int m = rg * 8 + k;
      uint4 vw = *(const uint4*)(Rp + m * 512 + 16 * (c32 ^ (m & 7)));
      long long grow = m0 + m;
      if (grow < M) {
        *(uint4*)(V + grow * 256 + c32 * 8) = vw;
        unsigned int ws[4] = {vw.x, vw.y, vw.z, vw.w};
#pragma unroll
        for (int kk = 0; kk < 8; kk++) {
          float xv = h2f((unsigned short)((ws[kk >> 1] >> ((kk & 1) * 16)) & 0xffff));
          s8[kk] += xv; q8[kk] += xv * xv;
        }
      }
    }
    __syncthreads();  // bar5: v reads done; Rp reusable as scratch
    float* shf = (float*)Rp;  // [256][17] sums + [256][17] sumsq = 34816 B
#pragma unroll
    for (int kk = 0; kk < 8; kk++) {
      int col = c32 * 8 + kk;
      shf[col * 17 + rg] = s8[kk];
      shf[4352 + col * 17 + rg] = q8[kk];
    }
    __syncthreads();  // bar6
    if (tid < 256) {
      float tot = 0.f;
#pragma unroll
      for (int g = 0; g < 16; g++) tot += shf[tid * 17 + g];
      atomicAdd(&gsum[tid], tot);
    } else {
      int col = tid - 256; float tot = 0.f;
#pragma unroll
      for (int g = 0; g < 16; g++) tot += shf[4352 + col * 17 + g];
      atomicAdd(&gsum[256 + col], tot);
    }
    unsigned char* tmp = Rp; Rp = Rq; Rq = tmp;  // Rq(A(t+1)) becomes Rp
  }
}

// MFMA fp16 GEMM (predictor only). Tile 128x128, BK=32, 4 waves.
#define SA 40    // padded A/B staging stride (fp16)
#define SP 136   // padded C-tile stride (fp16)
__global__ __launch_bounds__(256) void gemm_k(
    const unsigned short* __restrict__ A, const unsigned short* __restrict__ Bt,
    const float* __restrict__ bias, unsigned short* __restrict__ C,
    int M, int K, int relu, float* __restrict__ gsum) {
  __shared__ __align__(16) unsigned short smem[128 * SP];
  unsigned short* As = smem;
  unsigned short* Bs = smem + 128 * SA;
  int m0 = blockIdx.x * 128, n0 = blockIdx.y * 128;
  int tid = threadIdx.x;
  int wave = tid >> 6, lane = tid & 63;
  int wm = (wave >> 1) * 64, wnn = (wave & 1) * 64;
  int lrow = lane & 15, lqq = lane >> 4;
  f32x4 acc[4][4] = {};
  int ktiles = K >> 5;
  int srow = tid >> 2;
  int ch8 = (tid & 3) << 3;
  int rowA0 = m0 + srow;      rowA0 = rowA0 < M ? rowA0 : M - 1;
  int rowA1 = m0 + srow + 64; rowA1 = rowA1 < M ? rowA1 : M - 1;
  const unsigned short* pa0 = A + (long long)rowA0 * K + ch8;
  const unsigned short* pa1 = A + (long long)rowA1 * K + ch8;
  const unsigned short* pq0 = Bt + (long long)(n0 + srow) * K + ch8;
  const unsigned short* pq1 = Bt + (long long)(n0 + srow + 64) * K + ch8;
  uint4 va0 = *(const uint4*)pa0, va1 = *(const uint4*)pa1;
  uint4 vb0 = *(const uint4*)pq0, vb1 = *(const uint4*)pq1;
  int lo0 = srow * SA + ch8, lo1 = (srow + 64) * SA + ch8;
  for (int kt = 0; kt < ktiles; ++kt) {
    __syncthreads();
    *(uint4*)(As + lo0) = va0;
    *(uint4*)(As + lo1) = va1;
    *(uint4*)(Bs + lo0) = vb0;
    *(uint4*)(Bs + lo1) = vb1;
    __syncthreads();
    f16x8 af[4], bf[4];
#pragma unroll
    for (int r = 0; r < 4; r++)
      af[r] = *(const f16x8*)(As + (wm + 16 * r + lrow) * SA + lqq * 8);
#pragma unroll
    for (int c = 0; c < 4; c++)
      bf[c] = *(const f16x8*)(Bs + (wnn + 16 * c + lrow) * SA + lqq * 8);
    if (kt + 1 < ktiles) {
      int kb = (kt + 1) << 5;
      va0 = *(const uint4*)(pa0 + kb); va1 = *(const uint4*)(pa1 + kb);
      vb0 = *(const uint4*)(pq0 + kb); vb1 = *(const uint4*)(pq1 + kb);
    }
#pragma unroll
    for (int r = 0; r < 4; r++)
#pragma unroll
      for (int c = 0; c < 4; c++)
        acc[r][c] = __builtin_amdgcn_mfma_f32_16x16x32_f16(af[r], bf[c], acc[r][c], 0, 0, 0);
  }
  __syncthreads();
  unsigned short* Ct = smem;
#pragma unroll
  for (int c = 0; c < 4; c++) {
    int col = wnn + 16 * c + lrow;
    float bv = bias[n0 + col];
#pragma unroll
    for (int r = 0; r < 4; r++) {
      int rbase = wm + 16 * r + lqq * 4;
#pragma unroll
      for (int i = 0; i < 4; i++) {
        float v = acc[r][c][i] + bv;
        if (relu) v = fmaxf(v, 0.f);
        Ct[(rbase + i) * SP + col] = f2h16(v);
      }
    }
  }
  __syncthreads();
  int c16 = tid & 15, g = tid >> 4;
  float s8[8] = {}, q8[8] = {};
  bool dostats = (gsum != nullptr);
#pragma unroll
  for (int i = 0; i < 8; i++) {
    int row = g + i * 16;
    int grow = m0 + row;
    uint4 vw = *(const uint4*)(Ct + row * SP + c16 * 8);
    if (grow < M) {
      *(uint4*)(C + (long long)grow * 256 + n0 + c16 * 8) = vw;
      if (dostats) {
        unsigned int ws[4] = {vw.x, vw.y, vw.z, vw.w};
#pragma unroll
        for (int k = 0; k < 8; k++) {
          float xv = h2f((unsigned short)((ws[k >> 1] >> ((k & 1) * 16)) & 0xffff));
          s8[k] += xv; q8[k] += xv * xv;
        }
      }
    }
  }
  if (dostats) {
    float* shf = (float*)smem;
    __syncthreads();
#pragma unroll
    for (int k = 0; k < 8; k++) shf[(c16 * 8 + k) * 17 + g] = s8[k];
    __syncthreads();
    if (tid < 128) {
      float t = 0.f;
#pragma unroll
      for (int gg = 0; gg < 16; gg++) t += shf[tid * 17 + gg];
      atomicAdd(&gsum[n0 + tid], t);
    }
    __syncthreads();
#pragma unroll
    for (int k = 0; k < 8; k++) shf[(c16 * 8 + k) * 17 + g] = q8[k];
    __syncthreads();
    if (tid < 128) {
      float t = 0.f;
#pragma unroll
      for (int gg = 0; gg < 16; gg++) t += shf[tid * 17 + gg];
      atomicAdd(&gsum[256 + n0 + tid], t);
    }
  }
}

__global__ void bn_finalize_k(const float* __restrict__ gsum,
                              const float* __restrict__ pg, const float* __restrict__ pb,
                              int Nn, float* __restrict__ scale, float* __restrict__ shift) {
  int f = threadIdx.x;
  float inv = 1.f / (float)Nn;
  float mean = gsum[f] * inv;
  float var = fmaxf(gsum[256 + f] * inv - mean * mean, 0.f);
  float sc = pg[f] * rsqrtf(var + 1e-5f);
  scale[f] = sc;
  shift[f] = pb[f] - mean * sc;
}

// fused pool: mean over graph rows of relu(v*sc+sh)
__global__ void pool_fused_k(const unsigned short* __restrict__ v, const float* __restrict__ scale,
                             const float* __restrict__ shift, const int* __restrict__ gstart,
                             unsigned short* __restrict__ gout) {
  int g = blockIdx.x, f = threadIdx.x;
  int s = gstart[g], e = gstart[g + 1];
  float sc = scale[f], sh = shift[f];
  float acc = 0.f;
  for (int r = s; r < e; r++) acc += fmaxf(h2f(v[(long long)r * 256 + f]) * sc + sh, 0.f);
  gout[(long long)g * 256 + f] = f2h16(acc / fmaxf((float)(e - s), 1.f));
}
__global__ void pred2_k(const unsigned short* __restrict__ p1, const void* __restrict__ Wp2,
                        const void* __restrict__ bp2, void* __restrict__ out, int G,
                        const int* __restrict__ flags) {
  int wf32 = flags[1];
  int idx = blockIdx.x * blockDim.x + threadIdx.x;
  if (idx >= G * 12) return;
  int g = idx / 12, t = idx - g * 12;
  float acc = lin(bp2, t, wf32);
  const unsigned short* row = p1 + (long long)g * 256;
  for (int k = 0; k < 256; k++) acc += h2f(row[k]) * lin(Wp2, k * 12 + t, wf32);
  if (wf32) ((float*)out)[idx] = acc;
  else      ((unsigned short*)out)[idx] = f2b(acc);
}

extern "C" void kernel_launch(void* const* d_in, const int* in_sizes, int n_in,
                              void* d_out, int out_size, void* d_ws, size_t ws_size,
                              hipStream_t stream) {
  int wb = -1;
  for (int i = 3; i + 15 < n_in; i++) {
    if (in_sizes[i] == 32768 && in_sizes[i + 1] == 256 && in_sizes[i + 2] == 65536 &&
        in_sizes[i + 3] == 256 && in_sizes[i + 4] == 256 && in_sizes[i + 5] == 256 &&
        in_sizes[i + 6] == 262144) { wb = i; break; }
  }
  if (wb < 0) wb = (n_in >= 20) ? 4 : 3;

  const void* x      = d_in[0];
  const int*  edge   = (const int*)d_in[1];
  const int*  batch  = (const int*)d_in[2];
  const void* W1_0   = d_in[wb + 0];
  const void* b1_0   = d_in[wb + 1];
  const void* W2_0   = d_in[wb + 2];
  const void* b2_0   = d_in[wb + 3];
  const void* gamma0 = d_in[wb + 4];
  const void* beta0  = d_in[wb + 5];
  const void* W1s    = d_in[wb + 6];
  const void* b1s    = d_in[wb + 7];
  const void* W2s    = d_in[wb + 8];
  const void* b2s    = d_in[wb + 9];
  const void* gammas = d_in[wb + 10];
  const void* betas  = d_in[wb + 11];
  const void* Wp1    = d_in[wb + 12];
  const void* bp1    = d_in[wb + 13];
  const void* Wp2    = d_in[wb + 14];
  const void* bp2    = d_in[wb + 15];

  const int N = in_sizes[0] / 128;
  const int E = in_sizes[1] / 2;
  const int G = out_size / 12;
  const int H = 256;

  char* w = (char*)d_ws;
  size_t off = 0;
  auto alloc = [&](size_t bytes) -> char* {
    char* p = w + off;
    off += (bytes + 255) & ~(size_t)255;
    return p;
  };
  unsigned short* bufX  = (unsigned short*)alloc((size_t)N * H * 2);
  unsigned short* bufY  = (unsigned short*)alloc((size_t)N * H * 2);  // xh parks here first
  unsigned short* w1_0t = (unsigned short*)alloc((size_t)128 * 256 * 2);
  unsigned short* w2_0t = (unsigned short*)alloc((size_t)256 * 256 * 2);
  unsigned short* w1st  = (unsigned short*)alloc((size_t)4 * 256 * 256 * 2);
  unsigned short* w2st  = (unsigned short*)alloc((size_t)4 * 256 * 256 * 2);
  unsigned short* wp1t  = (unsigned short*)alloc((size_t)256 * 256 * 2);
  int*   rowptr   = (int*)alloc((size_t)(N + 1) * 4);
  int*   cnt      = (int*)alloc((size_t)N * 4);
  int*   colidx   = (int*)alloc((size_t)E * 4);
  int*   partials = (int*)alloc(1024 * 4);
  float* gsum     = (float*)alloc(512 * 4);
  float* bnscale  = (float*)alloc(256 * 4);
  float* bnshift  = (float*)alloc(256 * 4);
  float* pg       = (float*)alloc(256 * 4);
  float* pb       = (float*)alloc(256 * 4);
  float* pb1      = (float*)alloc(256 * 4);
  float* pb2      = (float*)alloc(256 * 4);
  int*   gstart   = (int*)alloc((size_t)(G + 1) * 4);
  int*   flags    = (int*)alloc(256);
  unsigned short* gpool = (unsigned short*)alloc((size_t)G * H * 2);
  unsigned short* p1    = (unsigned short*)alloc((size_t)G * H * 2);
  (void)ws_size; (void)n_in;

  detect_k<<<1, 64, 0, stream>>>(edge, (const unsigned short*)x, flags);

  // x -> fp16 into bufY (dead once layer-0 fused kernel overwrites bufY)
  convert_k<<<(int)(((long long)N * 128 / 4 + 255) / 256), 256, 0, stream>>>(
      x, bufY, (long long)N * 128, flags);

  dim3 tb(32, 8);
  auto transpose = [&](const void* src, long long eoff, unsigned short* dst, int R, int C) {
    transpose_off_k<<<dim3((C + 31) / 32, (R + 31) / 32), tb, 0, stream>>>(src, eoff, dst, R, C, flags);
  };
  transpose(W1_0, 0, w1_0t, 128, 256);
  transpose(W2_0, 0, w2_0t, 256, 256);
  for (int i = 0; i < 4; i++) {
    transpose(W1s, (long long)i * 65536, w1st + i * 65536, 256, 256);
    transpose(W2s, (long long)i * 65536, w2st + i * 65536, 256, 256);
  }
  transpose(Wp1, 0, wp1t, 256, 256);

  // CSR
  zero_i32_k<<<(N + 255) / 256, 256, 0, stream>>>(cnt, N);
  hist_k<<<(E + 255) / 256, 256, 0, stream>>>(edge, E, cnt, flags);
  int NB = (N + SCAN_CHUNK - 1) / SCAN_CHUNK;
  scan1_k<<<NB, 256, 0, stream>>>(cnt, rowptr, partials, N);
  scan2_k<<<1, 256, 0, stream>>>(partials, NB);
  scan3_k<<<NB, 256, 0, stream>>>(rowptr, partials, N, E);
  zero_i32_k<<<(N + 255) / 256, 256, 0, stream>>>(cnt, N);
  fill_k<<<(E + 255) / 256, 256, 0, stream>>>(edge, E, rowptr, cnt, colidx, flags);
  graph_bounds_k<<<(G + 1 + 255) / 256, 256, 0, stream>>>(batch, N, G, gstart, flags);

  const int ntiles = (N + 127) / 128;
  auto fused = [&](const unsigned short* Au, const unsigned short* w1, const unsigned short* w2,
                   unsigned short* Vv, int K) {
    if (K == 128)
      fused_layer_k<128><<<256, 512, 0, stream>>>(Au, w1, w2, pb1, pb2, Vv, N, ntiles, gsum);
    else
      fused_layer_k<256><<<256, 512, 0, stream>>>(Au, w1, w2, pb1, pb2, Vv, N, ntiles, gsum);
  };

  // ---- layer 0 ----
  prep_k<<<1, 256, 0, stream>>>(b1_0, b2_0, gamma0, beta0, 0, pb1, pb2, pg, pb, gsum, flags);
  gather_fused_k<16, 0><<<(N * 16 + 255) / 256, 256, 0, stream>>>(
      bufY, bnscale, bnshift, rowptr, colidx, bufX, N);
  fused(bufX, w1_0t, w2_0t, bufY, 128);   // v0 + fused BN stats -> bufY
  bn_finalize_k<<<1, 256, 0, stream>>>(gsum, pg, pb, N, bnscale, bnshift);
  unsigned short* cur = bufY;  // pre-BN v0
  unsigned short* oth = bufX;
  // ---- layers 1..4 ----
  for (int i = 0; i < 4; i++) {
    prep_k<<<1, 256, 0, stream>>>(b1s, b2s, gammas, betas, i * 256, pb1, pb2, pg, pb, gsum, flags);
    gather_fused_k<32, 1><<<(N * 32 + 255) / 256, 256, 0, stream>>>(
        cur, bnscale, bnshift, rowptr, colidx, oth, N);
    fused(oth, w1st + i * 65536, w2st + i * 65536, cur, 256);  // v_i + BN stats -> cur
    bn_finalize_k<<<1, 256, 0, stream>>>(gsum, pg, pb, N, bnscale, bnshift);
  }

  // ---- pool + predictor ----
  copy256_k<<<1, 256, 0, stream>>>(bp1, 0, pb1, flags);
  pool_fused_k<<<G, 256, 0, stream>>>(cur, bnscale, bnshift, gstart, gpool);
  gemm_k<<<dim3((G + 127) / 128, 2), 256, 0, stream>>>(gpool, wp1t, pb1, p1, G, 256, 1, nullptr);
  pred2_k<<<(G * 12 + 255) / 256, 256, 0, stream>>>(p1, Wp2, bp2, d_out, G, flags);
}

// Round 4
// 940.458 us; speedup vs baseline: 1.4104x; 1.0260x over previous
//
#include <hip/hip_runtime.h>

// GINModel on MI355X (gfx950). Round 10:
//  - fused_layer_k round-9 post-mortem: spills fixed (FETCH 176->27MB) but
//    96us/layer with MfmaUtil 10.5%, HBM 10.5%, Occ 17% = latency-bound.
//    Persistent 1-block/CU left a serial 6-barrier chain with nothing to
//    overlap it. Fix: de-persist. One block per 128-row tile (grid=782),
//    single 64KB LDS region (A -> h1 -> v -> BN scratch role swap),
//    2 blocks/CU co-resident: cross-block overlap hides barriers, weight-load
//    latency, and staggers the BN atomic bursts. Prefetch machinery removed
//    (A is L3-resident; 27MB fetch proves it).
//  - kt loops stay unroll-1 (round-9 spill fix).
// fp16 internal storage, fp32 accumulation, dual-width input hardening.

typedef __attribute__((ext_vector_type(4))) float f32x4;
typedef __attribute__((ext_vector_type(8))) _Float16 f16x8;

__device__ __forceinline__ float h2f(unsigned short u) {
  _Float16 h; __builtin_memcpy(&h, &u, 2); return (float)h;
}
__device__ __forceinline__ unsigned short f2h16(float f) {
  _Float16 h = (_Float16)f; unsigned short u; __builtin_memcpy(&u, &h, 2); return u;
}
__device__ __forceinline__ unsigned short f2b(float f) {  // fp32 -> bf16 RNE
  union { float f; unsigned int i; } c; c.f = f;
  unsigned int x = c.i;
  return (unsigned short)((x + 0x7fffu + ((x >> 16) & 1u)) >> 16);
}
__device__ __forceinline__ float lin(const void* p, long long i, int wf32) {
  if (wf32) return ((const float*)p)[i];
  union { unsigned int i; float f; } c;
  c.i = ((unsigned int)((const unsigned short*)p)[i]) << 16;
  return c.f;
}
__device__ __forceinline__ int ldidx(const int* p, long long i, int w64) {
  return w64 ? p[2 * i] : p[i];
}

// async global->LDS, 16B per lane; LDS dest = wave-uniform base + lane*16
__device__ __forceinline__ void gload_lds16(const void* g, void* l) {
  __builtin_amdgcn_global_load_lds(
      (const __attribute__((address_space(1))) unsigned int*)g,
      (__attribute__((address_space(3))) unsigned int*)l, 16, 0, 0);
}

// flags[0]=w64 (int64 indices), flags[1]=wf32 (fp32 floats)
__global__ void detect_k(const int* __restrict__ edge, const unsigned short* __restrict__ xa,
                         int* __restrict__ flags) {
  if (threadIdx.x != 0 || blockIdx.x != 0) return;
  int nzOdd = 0;
  for (int t = 0; t < 256; t++) if (edge[2 * t + 1] != 0) nzOdd++;
  flags[0] = (nzOdd == 0) ? 1 : 0;
  int plaus = 0;
  for (int t = 0; t < 64; t++) {
    unsigned short w = xa[2 * t];
    int e = (w >> 7) & 0xFF;
    if (w == 0 || (e >= 0x70 && e <= 0x85)) plaus++;
  }
  flags[1] = (plaus < 32) ? 1 : 0;
}

__global__ void zero_i32_k(int* __restrict__ p, int n) {
  int i = blockIdx.x * blockDim.x + threadIdx.x;
  if (i < n) p[i] = 0;
}

// per-layer prep: slice 4x256 params to fp32 + zero BN accumulators (512 f32)
__global__ void prep_k(const void* __restrict__ b1, const void* __restrict__ b2,
                       const void* __restrict__ gm, const void* __restrict__ bt, int eoff,
                       float* __restrict__ pb1, float* __restrict__ pb2,
                       float* __restrict__ pg, float* __restrict__ pb,
                       float* __restrict__ gsum, const int* __restrict__ flags) {
  int wf32 = flags[1], t = threadIdx.x;
  pb1[t] = lin(b1, (long long)eoff + t, wf32);
  pb2[t] = lin(b2, (long long)eoff + t, wf32);
  pg[t]  = lin(gm, (long long)eoff + t, wf32);
  pb[t]  = lin(bt, (long long)eoff + t, wf32);
  gsum[t] = 0.f; gsum[256 + t] = 0.f;
}
__global__ void copy256_k(const void* __restrict__ src, int eoff, float* __restrict__ dst,
                          const int* __restrict__ flags) {
  dst[threadIdx.x] = lin(src, (long long)eoff + threadIdx.x, flags[1]);
}

// input (R x C at element offset, dual width) -> fp16 transposed (C x R)
__global__ void transpose_off_k(const void* __restrict__ src, long long eoff,
                                unsigned short* __restrict__ dst, int R, int C,
                                const int* __restrict__ flags) {
  int wf32 = flags[1];
  __shared__ unsigned short t[32][33];
  int bx = blockIdx.x * 32, by = blockIdx.y * 32;
  int x = bx + threadIdx.x;
  for (int i = 0; i < 32; i += 8) {
    int y = by + threadIdx.y + i;
    if (y < R && x < C)
      t[threadIdx.y + i][threadIdx.x] = f2h16(lin(src, eoff + (long long)y * C + x, wf32));
  }
  __syncthreads();
  int x2 = by + threadIdx.x;
  for (int i = 0; i < 32; i += 8) {
    int y = bx + threadIdx.y + i;
    if (y < C && x2 < R) dst[(long long)y * R + x2] = t[threadIdx.x][threadIdx.y + i];
  }
}

// ---------------- CSR ----------------
__global__ void hist_k(const int* __restrict__ edge, int E, int* __restrict__ cnt,
                       const int* __restrict__ flags) {
  int w64 = flags[0];
  int e = blockIdx.x * blockDim.x + threadIdx.x;
  if (e < E) atomicAdd(&cnt[ldidx(edge, (long long)E + e, w64)], 1);
}
#define SCAN_CHUNK 1024
__global__ void scan1_k(const int* __restrict__ in, int* __restrict__ out,
                        int* __restrict__ partials, int n) {
  __shared__ int sh[256];
  int tid = threadIdx.x;
  int base = blockIdx.x * SCAN_CHUNK + tid * 4;
  int v[4]; int tsum = 0;
#pragma unroll
  for (int i = 0; i < 4; i++) { v[i] = (base + i < n) ? in[base + i] : 0; tsum += v[i]; }
  sh[tid] = tsum; __syncthreads();
  for (int off = 1; off < 256; off <<= 1) {
    int t = (tid >= off) ? sh[tid - off] : 0;
    __syncthreads();
    sh[tid] += t;
    __syncthreads();
  }
  int run = sh[tid] - tsum;
#pragma unroll
  for (int i = 0; i < 4; i++) { if (base + i < n) out[base + i] = run; run += v[i]; }
  if (tid == 255) partials[blockIdx.x] = sh[255];
}
__global__ void scan2_k(int* partials, int B) {
  __shared__ int sh[256];
  int tid = threadIdx.x;
  int orig = (tid < B) ? partials[tid] : 0;
  sh[tid] = orig; __syncthreads();
  for (int off = 1; off < 256; off <<= 1) {
    int t = (tid >= off) ? sh[tid - off] : 0;
    __syncthreads();
    sh[tid] += t;
    __syncthreads();
  }
  if (tid < B) partials[tid] = sh[tid] - orig;
}
__global__ void scan3_k(int* __restrict__ out, const int* __restrict__ partials,
                        int n, int total) {
  int base = blockIdx.x * SCAN_CHUNK + threadIdx.x * 4;
  int add = partials[blockIdx.x];
#pragma unroll
  for (int i = 0; i < 4; i++) { if (base + i < n) out[base + i] += add; }
  if (blockIdx.x == 0 && threadIdx.x == 0) out[n] = total;
}
__global__ void fill_k(const int* __restrict__ edge, int E, const int* __restrict__ rowptr,
                       int* __restrict__ cnt, int* __restrict__ colidx,
                       const int* __restrict__ flags) {
  int w64 = flags[0];
  int e = blockIdx.x * blockDim.x + threadIdx.x;
  if (e >= E) return;
  int s = ldidx(edge, e, w64);
  int d = ldidx(edge, (long long)E + e, w64);
  int p = atomicAdd(&cnt[d], 1);
  colidx[rowptr[d] + p] = s;
}
__global__ void graph_bounds_k(const int* __restrict__ b, int Nn, int G,
                               int* __restrict__ gstart, const int* __restrict__ flags) {
  int w64 = flags[0];
  int g = blockIdx.x * blockDim.x + threadIdx.x;
  if (g > G) return;
  int lo = 0, hi = Nn;
  while (lo < hi) {
    int mid = (lo + hi) >> 1;
    if (ldidx(b, mid, w64) < g) lo = mid + 1; else hi = mid;
  }
  gstart[g] = lo;
}

// x (dual width) -> fp16
__global__ void convert_k(const void* __restrict__ x, unsigned short* __restrict__ xh,
                          long long n, const int* __restrict__ flags) {
  int wf32 = flags[1];
  long long base = ((long long)blockIdx.x * blockDim.x + threadIdx.x) * 4;
  if (base >= n) return;
#pragma unroll
  for (int k = 0; k < 4; k++) xh[base + k] = f2h16(lin(x, base + k, wf32));
}

// fused aggregation: u[i] = hn(i) + sum_{j in nbrs(i)} hn(j)
// hn = APPLY ? relu(v*scale+shift) : v.  LPN lanes per node, 8 fp16 per lane.
template <int LPN, int APPLY>
__global__ void gather_fused_k(const unsigned short* __restrict__ src,
                               const float* __restrict__ scale, const float* __restrict__ shift,
                               const int* __restrict__ rowptr, const int* __restrict__ colidx,
                               unsigned short* __restrict__ u, int Nn) {
  const int F = LPN * 8;
  int gid = blockIdx.x * blockDim.x + threadIdx.x;
  int node = gid / LPN;
  if (node >= Nn) return;
  int fb = (gid % LPN) * 8;
  float sc[8], sh[8];
  if (APPLY) {
#pragma unroll
    for (int k = 0; k < 8; k++) { sc[k] = scale[fb + k]; sh[k] = shift[fb + k]; }
  }
  float acc[8];
  {
    uint4 raw = *(const uint4*)(src + (long long)node * F + fb);
    unsigned int ws[4] = {raw.x, raw.y, raw.z, raw.w};
#pragma unroll
    for (int k = 0; k < 8; k++) {
      float xv = h2f((unsigned short)((ws[k >> 1] >> ((k & 1) * 16)) & 0xffff));
      acc[k] = APPLY ? fmaxf(xv * sc[k] + sh[k], 0.f) : xv;
    }
  }
  int s = rowptr[node], e = rowptr[node + 1];
  for (int j = s; j < e; j++) {
    long long nb = colidx[j];
    uint4 raw = *(const uint4*)(src + nb * F + fb);
    unsigned int ws[4] = {raw.x, raw.y, raw.z, raw.w};
#pragma unroll
    for (int k = 0; k < 8; k++) {
      float xv = h2f((unsigned short)((ws[k >> 1] >> ((k & 1) * 16)) & 0xffff));
      acc[k] += APPLY ? fmaxf(xv * sc[k] + sh[k], 0.f) : xv;
    }
  }
  uint4 o;
  unsigned int wo[4];
#pragma unroll
  for (int p = 0; p < 4; p++)
    wo[p] = (unsigned int)f2h16(acc[2 * p]) | ((unsigned int)f2h16(acc[2 * p + 1]) << 16);
  o.x = wo[0]; o.y = wo[1]; o.z = wo[2]; o.w = wo[3];
  *(uint4*)(u + (long long)node * F + fb) = o;
}

// stage one 128-row A-tile into LDS region R via global_load_lds (width 16).
// LDS dest is linear (base + lane*16); the XOR swizzle is applied to the
// per-lane GLOBAL source chunk instead (inverse of the read-side XOR).
template <int KIN>
__device__ __forceinline__ void stage_tile_lds(
    const unsigned short* __restrict__ A, long long row0, int M,
    unsigned char* R, int tid) {
  const int lane = tid & 63, wave = tid >> 6;
  constexpr int ROWB = 2 * KIN;            // bytes per row (256 or 512)
  constexpr int CHUNKS = ROWB / 16;        // 16B chunks per row (16 or 32)
  constexpr int NISSUE = (128 * ROWB) / (8 * 1024);  // 4 or 8
#pragma unroll
  for (int j = 0; j < NISSUE; j++) {
    int slot = j * 8 + wave;               // which KB of the tile (wave-uniform)
    int baseRow = (slot * 1024) / ROWB;
    int row = baseRow + lane / CHUNKS;
    int ci = lane % CHUNKS;                // chunk slot this lane fills
    int c = ci ^ (row & 7);                // source chunk (inverse swizzle)
    long long rg = row0 + row;
    if (rg >= M) rg = M - 1;
    gload_lds16(A + rg * KIN + c * 8, R + slot * 1024);
  }
}

// =====================================================================
// fused_layer_k: per-layer v = (relu(u@W1+b1))@W2 + b2, + BN column stats.
// One block per 128-row tile (grid = ceil(M/128)), 512 threads (8 waves),
// single 64KB LDS region with role swap: A(t) -> h1 -> v-staging -> BN
// scratch (each transition fenced by a barrier). 2 blocks/CU co-resident
// (LDS 64KB, VGPR<=128 via launch_bounds(512,4)) so cross-block overlap
// hides the serial barrier chain, weight-load latency and atomic bursts.
// Both MFMA stages computed transposed (A-op = W rows, B-op = data rows) so
// each lane's 4 accum values are 4 consecutive cols of one row -> b64 packs.
// kt loops are unroll-1 (round-9: full unroll hoisted 32 global loads and
// spilled accumulators to scratch).
// =====================================================================
template <int KIN>
__global__ __launch_bounds__(512, 4) void fused_layer_k(
    const unsigned short* __restrict__ A, const unsigned short* __restrict__ W1t,
    const unsigned short* __restrict__ W2t, const float* __restrict__ b1,
    const float* __restrict__ b2, unsigned short* __restrict__ V,
    int M, float* __restrict__ gsum) {
  __shared__ __align__(16) unsigned char R[65536];
  const int tid = threadIdx.x;
  const int lane = tid & 63, wave = tid >> 6;
  const int l15 = lane & 15, lq = lane >> 4;
  const int wn = wave >> 1, wm = wave & 1;
  const int nb0 = wn * 64, mb0 = wm * 64;
  constexpr int KT1 = KIN / 32;       // stage-1 k-tiles (4 or 8)
  const long long m0 = (long long)blockIdx.x * 128;

  // ---- prologue: stage A tile ----
  stage_tile_lds<KIN>(A, m0, M, R, tid);
  __syncthreads();  // compiler drains vmcnt before barrier -> tile resident

  // ---- stage 1: h1T[n][m] = relu((u @ W1)^T + b1) ----
  f32x4 acc[4][4] = {};
#pragma unroll 1
  for (int kt = 0; kt < KT1; kt++) {
    f16x8 wf[4], uf[4];
#pragma unroll
    for (int r = 0; r < 4; r++)
      wf[r] = *(const f16x8*)(W1t + (long long)(nb0 + 16 * r + l15) * KIN + kt * 32 + lq * 8);
#pragma unroll
    for (int c = 0; c < 4; c++) {
      int m = mb0 + 16 * c + l15;
      uf[c] = *(const f16x8*)(R + m * (2 * KIN) + 16 * ((kt * 4 + lq) ^ (m & 7)));
    }
#pragma unroll
    for (int r = 0; r < 4; r++)
#pragma unroll
      for (int c = 0; c < 4; c++)
        acc[r][c] = __builtin_amdgcn_mfma_f32_16x16x32_f16(wf[r], uf[c], acc[r][c], 0, 0, 0);
  }
  __syncthreads();  // bar1: all stage-1 reads of A done
  // h1 -> R (row m, 512B stride, swizzled); bias + relu
#pragma unroll
  for (int r = 0; r < 4; r++) {
    int nbase = nb0 + 16 * r + lq * 4;
    float4 bv = *(const float4*)(b1 + nbase);
#pragma unroll
    for (int c = 0; c < 4; c++) {
      int m = mb0 + 16 * c + l15;
      unsigned int h0 = f2h16(fmaxf(acc[r][c][0] + bv.x, 0.f));
      unsigned int h1v = f2h16(fmaxf(acc[r][c][1] + bv.y, 0.f));
      unsigned int h2v = f2h16(fmaxf(acc[r][c][2] + bv.z, 0.f));
      unsigned int h3 = f2h16(fmaxf(acc[r][c][3] + bv.w, 0.f));
      uint2 pk; pk.x = h0 | (h1v << 16); pk.y = h2v | (h3 << 16);
      int by = m * 512 + 16 * ((nbase >> 3) ^ (m & 7)) + ((nbase & 7) << 1);
      *(uint2*)(R + by) = pk;
    }
  }
  __syncthreads();  // bar2: h1 visible
  // ---- stage 2: vT[n][m] = (h1 @ W2)^T + b2 ----
  f32x4 acc2[4][4] = {};
#pragma unroll 1
  for (int kt = 0; kt < 8; kt++) {
    f16x8 wf[4], hf[4];
#pragma unroll
    for (int r = 0; r < 4; r++)
      wf[r] = *(const f16x8*)(W2t + (long long)(nb0 + 16 * r + l15) * 256 + kt * 32 + lq * 8);
#pragma unroll
    for (int c = 0; c < 4; c++) {
      int m = mb0 + 16 * c + l15;
      hf[c] = *(const f16x8*)(R + m * 512 + 16 * ((kt * 4 + lq) ^ (m & 7)));
    }
#pragma unroll
    for (int r = 0; r < 4; r++)
#pragma unroll
      for (int c = 0; c < 4; c++)
        acc2[r][c] = __builtin_amdgcn_mfma_f32_16x16x32_f16(wf[r], hf[c], acc2[r][c], 0, 0, 0);
  }
  __syncthreads();  // bar3: all stage-2 reads of h1 done
  // v -> R ([m][n], swizzled); bias, no relu
#pragma unroll
  for (int r = 0; r < 4; r++) {
    int nbase = nb0 + 16 * r + lq * 4;
    float4 bv = *(const float4*)(b2 + nbase);
#pragma unroll
    for (int c = 0; c < 4; c++) {
      int m = mb0 + 16 * c + l15;
      unsigned int h0 = f2h16(acc2[r][c][0] + bv.x);
      unsigned int h1v = f2h16(acc2[r][c][1] + bv.y);
      unsigned int h2v = f2h16(acc2[r][c][2] + bv.z);
      unsigned int h3 = f2h16(acc2[r][c][3] + bv.w);
      uint2 pk; pk.x = h0 | (h1v << 16); pk.y = h2v | (h3 << 16);
      int by = m * 512 + 16 * ((nbase >> 3) ^ (m & 7)) + ((nbase & 7) << 1);
      *(uint2*)(R + by) = pk;
    }
  }
  __syncthreads();  // bar4: v tile complete
  // coalesced store + BN partials
  const int c32 = tid & 31, rg = tid >> 5;
  float s8[8] = {}, q8[8] = {};
#pragma unroll
  for (int k = 0; k < 8; k++) {
    int m = rg * 8 + k;
    uint4 vw = *(const uint4*)(R + m * 512 + 16 * (c32 ^ (m & 7)));
    long long grow = m0 + m;
    if (grow < M) {
      *(uint4*)(V + grow * 256 + c32 * 8) = vw;
      unsigned int ws[4] = {vw.x, vw.y, vw.z, vw.w};
#pragma unroll
      for (int kk = 0; kk < 8; kk++) {
        float xv = h2f((unsigned short)((ws[kk >> 1] >> ((kk & 1) * 16)) & 0xffff));
        s8[kk] += xv; q8[kk] += xv * xv;
      }
    }
  }
  __syncthreads();  // bar5: v reads done; R reusable as scratch
  float* shf = (float*)R;  // [256][17] sums + [256][17] sumsq = 34816 B
#pragma unroll
  for (int kk = 0; kk < 8; kk++) {
    int col = c32 * 8 + kk;
    shf[col * 17 + rg] = s8[kk];
    shf[4352 + col * 17 + rg] = q8[kk];
  }
  __syncthreads();  // bar6
  if (tid < 256) {
    float tot = 0.f;
#pragma unroll
    for (int g = 0; g < 16; g++) tot += shf[tid * 17 + g];
    atomicAdd(&gsum[tid], tot);
  } else {
    int col = tid - 256; float tot = 0.f;
#pragma unroll
    for (int g = 0; g < 16; g++) tot += shf[4352 + col * 17 + g];
    atomicAdd(&gsum[256 + col], tot);
  }
}

// MFMA fp16 GEMM (predictor only). Tile 128x128, BK=32, 4 waves.
#define SA 40    // padded A/B staging stride (fp16)
#define SP 136   // padded C-tile stride (fp16)
__global__ __launch_bounds__(256) void gemm_k(
    const unsigned short* __restrict__ A, const unsigned short* __restrict__ Bt,
    const float* __restrict__ bias, unsigned short* __restrict__ C,
    int M, int K, int relu, float* __restrict__ gsum) {
  __shared__ __align__(16) unsigned short smem[128 * SP];
  unsigned short* As = smem;
  unsigned short* Bs = smem + 128 * SA;
  int m0 = blockIdx.x * 128, n0 = blockIdx.y * 128;
  int tid = threadIdx.x;
  int wave = tid >> 6, lane = tid & 63;
  int wm = (wave >> 1) * 64, wnn = (wave & 1) * 64;
  int lrow = lane & 15, lqq = lane >> 4;
  f32x4 acc[4][4] = {};
  int ktiles = K >> 5;
  int srow = tid >> 2;
  int ch8 = (tid & 3) << 3;
  int rowA0 = m0 + srow;      rowA0 = rowA0 < M ? rowA0 : M - 1;
  int rowA1 = m0 + srow + 64; rowA1 = rowA1 < M ? rowA1 : M - 1;
  const unsigned short* pa0 = A + (long long)rowA0 * K + ch8;
  const unsigned short* pa1 = A + (long long)rowA1 * K + ch8;
  const unsigned short* pq0 = Bt + (long long)(n0 + srow) * K + ch8;
  const unsigned short* pq1 = Bt + (long long)(n0 + srow + 64) * K + ch8;
  uint4 va0 = *(const uint4*)pa0, va1 = *(const uint4*)pa1;
  uint4 vb0 = *(const uint4*)pq0, vb1 = *(const uint4*)pq1;
  int lo0 = srow * SA + ch8, lo1 = (srow + 64) * SA + ch8;
  for (int kt = 0; kt < ktiles; ++kt) {
    __syncthreads();
    *(uint4*)(As + lo0) = va0;
    *(uint4*)(As + lo1) = va1;
    *(uint4*)(Bs + lo0) = vb0;
    *(uint4*)(Bs + lo1) = vb1;
    __syncthreads();
    f16x8 af[4], bf[4];
#pragma unroll
    for (int r = 0; r < 4; r++)
      af[r] = *(const f16x8*)(As + (wm + 16 * r + lrow) * SA + lqq * 8);
#pragma unroll
    for (int c = 0; c < 4; c++)
      bf[c] = *(const f16x8*)(Bs + (wnn + 16 * c + lrow) * SA + lqq * 8);
    if (kt + 1 < ktiles) {
      int kb = (kt + 1) << 5;
      va0 = *(const uint4*)(pa0 + kb); va1 = *(const uint4*)(pa1 + kb);
      vb0 = *(const uint4*)(pq0 + kb); vb1 = *(const uint4*)(pq1 + kb);
    }
#pragma unroll
    for (int r = 0; r < 4; r++)
#pragma unroll
      for (int c = 0; c < 4; c++)
        acc[r][c] = __builtin_amdgcn_mfma_f32_16x16x32_f16(af[r], bf[c], acc[r][c], 0, 0, 0);
  }
  __syncthreads();
  unsigned short* Ct = smem;
#pragma unroll
  for (int c = 0; c < 4; c++) {
    int col = wnn + 16 * c + lrow;
    float bv = bias[n0 + col];
#pragma unroll
    for (int r = 0; r < 4; r++) {
      int rbase = wm + 16 * r + lqq * 4;
#pragma unroll
      for (int i = 0; i < 4; i++) {
        float v = acc[r][c][i] + bv;
        if (relu) v = fmaxf(v, 0.f);
        Ct[(rbase + i) * SP + col] = f2h16(v);
      }
    }
  }
  __syncthreads();
  int c16 = tid & 15, g = tid >> 4;
  float s8[8] = {}, q8[8] = {};
  bool dostats = (gsum != nullptr);
#pragma unroll
  for (int i = 0; i < 8; i++) {
    int row = g + i * 16;
    int grow = m0 + row;
    uint4 vw = *(const uint4*)(Ct + row * SP + c16 * 8);
    if (grow < M) {
      *(uint4*)(C + (long long)grow * 256 + n0 + c16 * 8) = vw;
      if (dostats) {
        unsigned int ws[4] = {vw.x, vw.y, vw.z, vw.w};
#pragma unroll
        for (int k = 0; k < 8; k++) {
          float xv = h2f((unsigned short)((ws[k >> 1] >> ((k & 1) * 16)) & 0xffff));
          s8[k] += xv; q8[k] += xv * xv;
        }
      }
    }
  }
  if (dostats) {
    float* shf = (float*)smem;
    __syncthreads();
#pragma unroll
    for (int k = 0; k < 8; k++) shf[(c16 * 8 + k) * 17 + g] = s8[k];
    __syncthreads();
    if (tid < 128) {
      float t = 0.f;
#pragma unroll
      for (int gg = 0; gg < 16; gg++) t += shf[tid * 17 + gg];
      atomicAdd(&gsum[n0 + tid], t);
    }
    __syncthreads();
#pragma unroll
    for (int k = 0; k < 8; k++) shf[(c16 * 8 + k) * 17 + g] = q8[k];
    __syncthreads();
    if (tid < 128) {
      float t = 0.f;
#pragma unroll
      for (int gg = 0; gg < 16; gg++) t += shf[tid * 17 + gg];
      atomicAdd(&gsum[256 + n0 + tid], t);
    }
  }
}

__global__ void bn_finalize_k(const float* __restrict__ gsum,
                              const float* __restrict__ pg, const float* __restrict__ pb,
                              int Nn, float* __restrict__ scale, float* __restrict__ shift) {
  int f = threadIdx.x;
  float inv = 1.f / (float)Nn;
  float mean = gsum[f] * inv;
  float var = fmaxf(gsum[256 + f] * inv - mean * mean, 0.f);
  float sc = pg[f] * rsqrtf(var + 1e-5f);
  scale[f] = sc;
  shift[f] = pb[f] - mean * sc;
}

// fused pool: mean over graph rows of relu(v*sc+sh)
__global__ void pool_fused_k(const unsigned short* __restrict__ v, const float* __restrict__ scale,
                             const float* __restrict__ shift, const int* __restrict__ gstart,
                             unsigned short* __restrict__ gout) {
  int g = blockIdx.x, f = threadIdx.x;
  int s = gstart[g], e = gstart[g + 1];
  float sc = scale[f], sh = shift[f];
  float acc = 0.f;
  for (int r = s; r < e; r++) acc += fmaxf(h2f(v[(long long)r * 256 + f]) * sc + sh, 0.f);
  gout[(long long)g * 256 + f] = f2h16(acc / fmaxf((float)(e - s), 1.f));
}
__global__ void pred2_k(const unsigned short* __restrict__ p1, const void* __restrict__ Wp2,
                        const void* __restrict__ bp2, void* __restrict__ out, int G,
                        const int* __restrict__ flags) {
  int wf32 = flags[1];
  int idx = blockIdx.x * blockDim.x + threadIdx.x;
  if (idx >= G * 12) return;
  int g = idx / 12, t = idx - g * 12;
  float acc = lin(bp2, t, wf32);
  const unsigned short* row = p1 + (long long)g * 256;
  for (int k = 0; k < 256; k++) acc += h2f(row[k]) * lin(Wp2, k * 12 + t, wf32);
  if (wf32) ((float*)out)[idx] = acc;
  else      ((unsigned short*)out)[idx] = f2b(acc);
}

extern "C" void kernel_launch(void* const* d_in, const int* in_sizes, int n_in,
                              void* d_out, int out_size, void* d_ws, size_t ws_size,
                              hipStream_t stream) {
  int wb = -1;
  for (int i = 3; i + 15 < n_in; i++) {
    if (in_sizes[i] == 32768 && in_sizes[i + 1] == 256 && in_sizes[i + 2] == 65536 &&
        in_sizes[i + 3] == 256 && in_sizes[i + 4] == 256 && in_sizes[i + 5] == 256 &&
        in_sizes[i + 6] == 262144) { wb = i; break; }
  }
  if (wb < 0) wb = (n_in >= 20) ? 4 : 3;

  const void* x      = d_in[0];
  const int*  edge   = (const int*)d_in[1];
  const int*  batch  = (const int*)d_in[2];
  const void* W1_0   = d_in[wb + 0];
  const void* b1_0   = d_in[wb + 1];
  const void* W2_0   = d_in[wb + 2];
  const void* b2_0   = d_in[wb + 3];
  const void* gamma0 = d_in[wb + 4];
  const void* beta0  = d_in[wb + 5];
  const void* W1s    = d_in[wb + 6];
  const void* b1s    = d_in[wb + 7];
  const void* W2s    = d_in[wb + 8];
  const void* b2s    = d_in[wb + 9];
  const void* gammas = d_in[wb + 10];
  const void* betas  = d_in[wb + 11];
  const void* Wp1    = d_in[wb + 12];
  const void* bp1    = d_in[wb + 13];
  const void* Wp2    = d_in[wb + 14];
  const void* bp2    = d_in[wb + 15];

  const int N = in_sizes[0] / 128;
  const int E = in_sizes[1] / 2;
  const int G = out_size / 12;
  const int H = 256;

  char* w = (char*)d_ws;
  size_t off = 0;
  auto alloc = [&](size_t bytes) -> char* {
    char* p = w + off;
    off += (bytes + 255) & ~(size_t)255;
    return p;
  };
  unsigned short* bufX  = (unsigned short*)alloc((size_t)N * H * 2);
  unsigned short* bufY  = (unsigned short*)alloc((size_t)N * H * 2);  // xh parks here first
  unsigned short* w1_0t = (unsigned short*)alloc((size_t)128 * 256 * 2);
  unsigned short* w2_0t = (unsigned short*)alloc((size_t)256 * 256 * 2);
  unsigned short* w1st  = (unsigned short*)alloc((size_t)4 * 256 * 256 * 2);
  unsigned short* w2st  = (unsigned short*)alloc((size_t)4 * 256 * 256 * 2);
  unsigned short* wp1t  = (unsigned short*)alloc((size_t)256 * 256 * 2);
  int*   rowptr   = (int*)alloc((size_t)(N + 1) * 4);
  int*   cnt      = (int*)alloc((size_t)N * 4);
  int*   colidx   = (int*)alloc((size_t)E * 4);
  int*   partials = (int*)alloc(1024 * 4);
  float* gsum     = (float*)alloc(512 * 4);
  float* bnscale  = (float*)alloc(256 * 4);
  float* bnshift  = (float*)alloc(256 * 4);
  float* pg       = (float*)alloc(256 * 4);
  float* pb       = (float*)alloc(256 * 4);
  float* pb1      = (float*)alloc(256 * 4);
  float* pb2      = (float*)alloc(256 * 4);
  int*   gstart   = (int*)alloc((size_t)(G + 1) * 4);
  int*   flags    = (int*)alloc(256);
  unsigned short* gpool = (unsigned short*)alloc((size_t)G * H * 2);
  unsigned short* p1    = (unsigned short*)alloc((size_t)G * H * 2);
  (void)ws_size; (void)n_in;

  detect_k<<<1, 64, 0, stream>>>(edge, (const unsigned short*)x, flags);

  // x -> fp16 into bufY (dead once layer-0 fused kernel overwrites bufY)
  convert_k<<<(int)(((long long)N * 128 / 4 + 255) / 256), 256, 0, stream>>>(
      x, bufY, (long long)N * 128, flags);

  dim3 tb(32, 8);
  auto transpose = [&](const void* src, long long eoff, unsigned short* dst, int R, int C) {
    transpose_off_k<<<dim3((C + 31) / 32, (R + 31) / 32), tb, 0, stream>>>(src, eoff, dst, R, C, flags);
  };
  transpose(W1_0, 0, w1_0t, 128, 256);
  transpose(W2_0, 0, w2_0t, 256, 256);
  for (int i = 0; i < 4; i++) {
    transpose(W1s, (long long)i * 65536, w1st + i * 65536, 256, 256);
    transpose(W2s, (long long)i * 65536, w2st + i * 65536, 256, 256);
  }
  transpose(Wp1, 0, wp1t, 256, 256);

  // CSR
  zero_i32_k<<<(N + 255) / 256, 256, 0, stream>>>(cnt, N);
  hist_k<<<(E + 255) / 256, 256, 0, stream>>>(edge, E, cnt, flags);
  int NB = (N + SCAN_CHUNK - 1) / SCAN_CHUNK;
  scan1_k<<<NB, 256, 0, stream>>>(cnt, rowptr, partials, N);
  scan2_k<<<1, 256, 0, stream>>>(partials, NB);
  scan3_k<<<NB, 256, 0, stream>>>(rowptr, partials, N, E);
  zero_i32_k<<<(N + 255) / 256, 256, 0, stream>>>(cnt, N);
  fill_k<<<(E + 255) / 256, 256, 0, stream>>>(edge, E, rowptr, cnt, colidx, flags);
  graph_bounds_k<<<(G + 1 + 255) / 256, 256, 0, stream>>>(batch, N, G, gstart, flags);

  const int ntiles = (N + 127) / 128;
  auto fused = [&](const unsigned short* Au, const unsigned short* w1, const unsigned short* w2,
                   unsigned short* Vv, int K) {
    if (K == 128)
      fused_layer_k<128><<<ntiles, 512, 0, stream>>>(Au, w1, w2, pb1, pb2, Vv, N, gsum);
    else
      fused_layer_k<256><<<ntiles, 512, 0, stream>>>(Au, w1, w2, pb1, pb2, Vv, N, gsum);
  };

  // ---- layer 0 ----
  prep_k<<<1, 256, 0, stream>>>(b1_0, b2_0, gamma0, beta0, 0, pb1, pb2, pg, pb, gsum, flags);
  gather_fused_k<16, 0><<<(N * 16 + 255) / 256, 256, 0, stream>>>(
      bufY, bnscale, bnshift, rowptr, colidx, bufX, N);
  fused(bufX, w1_0t, w2_0t, bufY, 128);   // v0 + fused BN stats -> bufY
  bn_finalize_k<<<1, 256, 0, stream>>>(gsum, pg, pb, N, bnscale, bnshift);
  unsigned short* cur = bufY;  // pre-BN v0
  unsigned short* oth = bufX;
  // ---- layers 1..4 ----
  for (int i = 0; i < 4; i++) {
    prep_k<<<1, 256, 0, stream>>>(b1s, b2s, gammas, betas, i * 256, pb1, pb2, pg, pb, gsum, flags);
    gather_fused_k<32, 1><<<(N * 32 + 255) / 256, 256, 0, stream>>>(
        cur, bnscale, bnshift, rowptr, colidx, oth, N);
    fused(oth, w1st + i * 65536, w2st + i * 65536, cur, 256);  // v_i + BN stats -> cur
    bn_finalize_k<<<1, 256, 0, stream>>>(gsum, pg, pb, N, bnscale, bnshift);
  }

  // ---- pool + predictor ----
  copy256_k<<<1, 256, 0, stream>>>(bp1, 0, pb1, flags);
  pool_fused_k<<<G, 256, 0, stream>>>(cur, bnscale, bnshift, gstart, gpool);
  gemm_k<<<dim3((G + 127) / 128, 2), 256, 0, stream>>>(gpool, wp1t, pb1, p1, G, 256, 1, nullptr);
  pred2_k<<<(G * 12 + 255) / 256, 256, 0, stream>>>(p1, Wp2, bp2, d_out, G, flags);
}

// Round 5
// 897.236 us; speedup vs baseline: 1.4783x; 1.0482x over previous
//
#include <hip/hip_runtime.h>

// GINModel on MI355X (gfx950). Round 11:
//  - Round-10 post-mortem: per-block latency ~30-45us vs ~10us component
//    model; 2-block co-residency gained little (identically-phased serial
//    chains + contended BN atomics + acc=64 AGPR capping TLP at 16 waves/CU).
//  - fused_layer_k rebuilt on 64-row tiles: 8 waves x 32-col n-slices,
//    acc[2][4]=32 AGPRs, LDS 36KB -> launch_bounds(512,6) = 3 blocks/CU
//    (24 waves/CU), phase-staggered blocks hide load latency.
//  - gsum 32-way banked by blockIdx (contention 782 -> ~49 per address);
//    bn_finalize sums banks; prep zeroes 32x512.
//  - s_setprio(1) around MFMA clusters (cross-block role diversity).
//  - kt loops stay unroll-1 (round-9 spill lesson).
// fp16 internal storage, fp32 accumulation, dual-width input hardening.

typedef __attribute__((ext_vector_type(4))) float f32x4;
typedef __attribute__((ext_vector_type(8))) _Float16 f16x8;

__device__ __forceinline__ float h2f(unsigned short u) {
  _Float16 h; __builtin_memcpy(&h, &u, 2); return (float)h;
}
__device__ __forceinline__ unsigned short f2h16(float f) {
  _Float16 h = (_Float16)f; unsigned short u; __builtin_memcpy(&u, &h, 2); return u;
}
__device__ __forceinline__ unsigned short f2b(float f) {  // fp32 -> bf16 RNE
  union { float f; unsigned int i; } c; c.f = f;
  unsigned int x = c.i;
  return (unsigned short)((x + 0x7fffu + ((x >> 16) & 1u)) >> 16);
}
__device__ __forceinline__ float lin(const void* p, long long i, int wf32) {
  if (wf32) return ((const float*)p)[i];
  union { unsigned int i; float f; } c;
  c.i = ((unsigned int)((const unsigned short*)p)[i]) << 16;
  return c.f;
}
__device__ __forceinline__ int ldidx(const int* p, long long i, int w64) {
  return w64 ? p[2 * i] : p[i];
}

// async global->LDS, 16B per lane; LDS dest = wave-uniform base + lane*16
__device__ __forceinline__ void gload_lds16(const void* g, void* l) {
  __builtin_amdgcn_global_load_lds(
      (const __attribute__((address_space(1))) unsigned int*)g,
      (__attribute__((address_space(3))) unsigned int*)l, 16, 0, 0);
}

// flags[0]=w64 (int64 indices), flags[1]=wf32 (fp32 floats)
__global__ void detect_k(const int* __restrict__ edge, const unsigned short* __restrict__ xa,
                         int* __restrict__ flags) {
  if (threadIdx.x != 0 || blockIdx.x != 0) return;
  int nzOdd = 0;
  for (int t = 0; t < 256; t++) if (edge[2 * t + 1] != 0) nzOdd++;
  flags[0] = (nzOdd == 0) ? 1 : 0;
  int plaus = 0;
  for (int t = 0; t < 64; t++) {
    unsigned short w = xa[2 * t];
    int e = (w >> 7) & 0xFF;
    if (w == 0 || (e >= 0x70 && e <= 0x85)) plaus++;
  }
  flags[1] = (plaus < 32) ? 1 : 0;
}

__global__ void zero_i32_k(int* __restrict__ p, int n) {
  int i = blockIdx.x * blockDim.x + threadIdx.x;
  if (i < n) p[i] = 0;
}

// per-layer prep: slice 4x256 params to fp32 + zero 32-banked BN accumulators
__global__ void prep_k(const void* __restrict__ b1, const void* __restrict__ b2,
                       const void* __restrict__ gm, const void* __restrict__ bt, int eoff,
                       float* __restrict__ pb1, float* __restrict__ pb2,
                       float* __restrict__ pg, float* __restrict__ pb,
                       float* __restrict__ gsum, const int* __restrict__ flags) {
  int wf32 = flags[1], t = threadIdx.x;
  pb1[t] = lin(b1, (long long)eoff + t, wf32);
  pb2[t] = lin(b2, (long long)eoff + t, wf32);
  pg[t]  = lin(gm, (long long)eoff + t, wf32);
  pb[t]  = lin(bt, (long long)eoff + t, wf32);
  for (int i = t; i < 32 * 512; i += 256) gsum[i] = 0.f;
}
__global__ void copy256_k(const void* __restrict__ src, int eoff, float* __restrict__ dst,
                          const int* __restrict__ flags) {
  dst[threadIdx.x] = lin(src, (long long)eoff + threadIdx.x, flags[1]);
}

// input (R x C at element offset, dual width) -> fp16 transposed (C x R)
__global__ void transpose_off_k(const void* __restrict__ src, long long eoff,
                                unsigned short* __restrict__ dst, int R, int C,
                                const int* __restrict__ flags) {
  int wf32 = flags[1];
  __shared__ unsigned short t[32][33];
  int bx = blockIdx.x * 32, by = blockIdx.y * 32;
  int x = bx + threadIdx.x;
  for (int i = 0; i < 32; i += 8) {
    int y = by + threadIdx.y + i;
    if (y < R && x < C)
      t[threadIdx.y + i][threadIdx.x] = f2h16(lin(src, eoff + (long long)y * C + x, wf32));
  }
  __syncthreads();
  int x2 = by + threadIdx.x;
  for (int i = 0; i < 32; i += 8) {
    int y = bx + threadIdx.y + i;
    if (y < C && x2 < R) dst[(long long)y * R + x2] = t[threadIdx.x][threadIdx.y + i];
  }
}

// ---------------- CSR ----------------
__global__ void hist_k(const int* __restrict__ edge, int E, int* __restrict__ cnt,
                       const int* __restrict__ flags) {
  int w64 = flags[0];
  int e = blockIdx.x * blockDim.x + threadIdx.x;
  if (e < E) atomicAdd(&cnt[ldidx(edge, (long long)E + e, w64)], 1);
}
#define SCAN_CHUNK 1024
__global__ void scan1_k(const int* __restrict__ in, int* __restrict__ out,
                        int* __restrict__ partials, int n) {
  __shared__ int sh[256];
  int tid = threadIdx.x;
  int base = blockIdx.x * SCAN_CHUNK + tid * 4;
  int v[4]; int tsum = 0;
#pragma unroll
  for (int i = 0; i < 4; i++) { v[i] = (base + i < n) ? in[base + i] : 0; tsum += v[i]; }
  sh[tid] = tsum; __syncthreads();
  for (int off = 1; off < 256; off <<= 1) {
    int t = (tid >= off) ? sh[tid - off] : 0;
    __syncthreads();
    sh[tid] += t;
    __syncthreads();
  }
  int run = sh[tid] - tsum;
#pragma unroll
  for (int i = 0; i < 4; i++) { if (base + i < n) out[base + i] = run; run += v[i]; }
  if (tid == 255) partials[blockIdx.x] = sh[255];
}
__global__ void scan2_k(int* partials, int B) {
  __shared__ int sh[256];
  int tid = threadIdx.x;
  int orig = (tid < B) ? partials[tid] : 0;
  sh[tid] = orig; __syncthreads();
  for (int off = 1; off < 256; off <<= 1) {
    int t = (tid >= off) ? sh[tid - off] : 0;
    __syncthreads();
    sh[tid] += t;
    __syncthreads();
  }
  if (tid < B) partials[tid] = sh[tid] - orig;
}
__global__ void scan3_k(int* __restrict__ out, const int* __restrict__ partials,
                        int n, int total) {
  int base = blockIdx.x * SCAN_CHUNK + threadIdx.x * 4;
  int add = partials[blockIdx.x];
#pragma unroll
  for (int i = 0; i < 4; i++) { if (base + i < n) out[base + i] += add; }
  if (blockIdx.x == 0 && threadIdx.x == 0) out[n] = total;
}
__global__ void fill_k(const int* __restrict__ edge, int E, const int* __restrict__ rowptr,
                       int* __restrict__ cnt, int* __restrict__ colidx,
                       const int* __restrict__ flags) {
  int w64 = flags[0];
  int e = blockIdx.x * blockDim.x + threadIdx.x;
  if (e >= E) return;
  int s = ldidx(edge, e, w64);
  int d = ldidx(edge, (long long)E + e, w64);
  int p = atomicAdd(&cnt[d], 1);
  colidx[rowptr[d] + p] = s;
}
__global__ void graph_bounds_k(const int* __restrict__ b, int Nn, int G,
                               int* __restrict__ gstart, const int* __restrict__ flags) {
  int w64 = flags[0];
  int g = blockIdx.x * blockDim.x + threadIdx.x;
  if (g > G) return;
  int lo = 0, hi = Nn;
  while (lo < hi) {
    int mid = (lo + hi) >> 1;
    if (ldidx(b, mid, w64) < g) lo = mid + 1; else hi = mid;
  }
  gstart[g] = lo;
}

// x (dual width) -> fp16
__global__ void convert_k(const void* __restrict__ x, unsigned short* __restrict__ xh,
                          long long n, const int* __restrict__ flags) {
  int wf32 = flags[1];
  long long base = ((long long)blockIdx.x * blockDim.x + threadIdx.x) * 4;
  if (base >= n) return;
#pragma unroll
  for (int k = 0; k < 4; k++) xh[base + k] = f2h16(lin(x, base + k, wf32));
}

// fused aggregation: u[i] = hn(i) + sum_{j in nbrs(i)} hn(j)
// hn = APPLY ? relu(v*scale+shift) : v.  LPN lanes per node, 8 fp16 per lane.
template <int LPN, int APPLY>
__global__ void gather_fused_k(const unsigned short* __restrict__ src,
                               const float* __restrict__ scale, const float* __restrict__ shift,
                               const int* __restrict__ rowptr, const int* __restrict__ colidx,
                               unsigned short* __restrict__ u, int Nn) {
  const int F = LPN * 8;
  int gid = blockIdx.x * blockDim.x + threadIdx.x;
  int node = gid / LPN;
  if (node >= Nn) return;
  int fb = (gid % LPN) * 8;
  float sc[8], sh[8];
  if (APPLY) {
#pragma unroll
    for (int k = 0; k < 8; k++) { sc[k] = scale[fb + k]; sh[k] = shift[fb + k]; }
  }
  float acc[8];
  {
    uint4 raw = *(const uint4*)(src + (long long)node * F + fb);
    unsigned int ws[4] = {raw.x, raw.y, raw.z, raw.w};
#pragma unroll
    for (int k = 0; k < 8; k++) {
      float xv = h2f((unsigned short)((ws[k >> 1] >> ((k & 1) * 16)) & 0xffff));
      acc[k] = APPLY ? fmaxf(xv * sc[k] + sh[k], 0.f) : xv;
    }
  }
  int s = rowptr[node], e = rowptr[node + 1];
  for (int j = s; j < e; j++) {
    long long nb = colidx[j];
    uint4 raw = *(const uint4*)(src + nb * F + fb);
    unsigned int ws[4] = {raw.x, raw.y, raw.z, raw.w};
#pragma unroll
    for (int k = 0; k < 8; k++) {
      float xv = h2f((unsigned short)((ws[k >> 1] >> ((k & 1) * 16)) & 0xffff));
      acc[k] += APPLY ? fmaxf(xv * sc[k] + sh[k], 0.f) : xv;
    }
  }
  uint4 o;
  unsigned int wo[4];
#pragma unroll
  for (int p = 0; p < 4; p++)
    wo[p] = (unsigned int)f2h16(acc[2 * p]) | ((unsigned int)f2h16(acc[2 * p + 1]) << 16);
  o.x = wo[0]; o.y = wo[1]; o.z = wo[2]; o.w = wo[3];
  *(uint4*)(u + (long long)node * F + fb) = o;
}

// stage one 64-row A-tile into LDS region R via global_load_lds (width 16).
// LDS dest is linear (base + lane*16); XOR swizzle applied to per-lane GLOBAL
// source chunk (inverse of read-side XOR) per rule #21.
template <int KIN>
__device__ __forceinline__ void stage_tile64(
    const unsigned short* __restrict__ A, long long row0, int M,
    unsigned char* R, int tid) {
  const int lane = tid & 63, wave = tid >> 6;
  constexpr int ROWB = 2 * KIN;            // bytes per row (256 or 512)
  constexpr int CHUNKS = ROWB / 16;        // 16B chunks per row (16 or 32)
  constexpr int NISSUE = (64 * ROWB) / (8 * 1024);  // 2 or 4
#pragma unroll
  for (int j = 0; j < NISSUE; j++) {
    int slot = j * 8 + wave;               // which KB of the tile (wave-uniform)
    int baseRow = (slot * 1024) / ROWB;
    int row = baseRow + lane / CHUNKS;
    int ci = lane % CHUNKS;                // chunk slot this lane fills
    int c = ci ^ (row & 7);                // source chunk (inverse swizzle)
    long long rg = row0 + row;
    if (rg >= M) rg = M - 1;
    gload_lds16(A + rg * KIN + c * 8, R + slot * 1024);
  }
}

// =====================================================================
// fused_layer_k: per-layer v = (relu(u@W1+b1))@W2 + b2, + BN column stats.
// One block per 64-row tile (grid = ceil(M/64)), 512 threads = 8 waves,
// each wave owns a 32-col n-slice (acc[2][4] = 32 AGPRs). LDS 36KB with
// role swap: A(32KB) -> h1(32KB) -> v(32KB) -> BN scratch(34.8KB... 36KB).
// launch_bounds(512,6) -> 3 blocks/CU (24 waves/CU), phase-staggered blocks
// hide weight-load latency, staging drains and atomic bursts.
// BN atomics 32-way banked by blockIdx to kill L2 RMW contention.
// Both MFMA stages computed transposed (A-op = W rows, B-op = data rows) so
// each lane's 4 accum values are 4 consecutive cols of one row -> b64 packs.
// kt loops unroll-1 (round-9: full unroll hoists loads -> spills).
// =====================================================================
template <int KIN>
__global__ __launch_bounds__(512, 6) void fused_layer_k(
    const unsigned short* __restrict__ A, const unsigned short* __restrict__ W1t,
    const unsigned short* __restrict__ W2t, const float* __restrict__ b1,
    const float* __restrict__ b2, unsigned short* __restrict__ V,
    int M, float* __restrict__ gsum) {
  __shared__ __align__(16) unsigned char R[36864];
  const int tid = threadIdx.x;
  const int lane = tid & 63, wave = tid >> 6;   // wave 0..7
  const int l15 = lane & 15, lq = lane >> 4;    // lq 0..3
  const int nb0 = wave * 32;                    // n-slice base (32 cols/wave)
  constexpr int KT1 = KIN / 32;                 // stage-1 k-tiles (4 or 8)
  const long long m0 = (long long)blockIdx.x * 64;

  // ---- prologue: stage A tile (64 x KIN) ----
  stage_tile64<KIN>(A, m0, M, R, tid);
  __syncthreads();  // vmcnt(0) drained at barrier -> tile resident

  // ---- stage 1: h1T[n][m] = relu((u @ W1)^T + b1) ----
  f32x4 acc[2][4] = {};
  __builtin_amdgcn_s_setprio(1);
#pragma unroll 1
  for (int kt = 0; kt < KT1; kt++) {
    f16x8 wf[2], uf[4];
#pragma unroll
    for (int r = 0; r < 2; r++)
      wf[r] = *(const f16x8*)(W1t + (long long)(nb0 + 16 * r + l15) * KIN + kt * 32 + lq * 8);
#pragma unroll
    for (int c = 0; c < 4; c++) {
      int m = 16 * c + l15;
      uf[c] = *(const f16x8*)(R + m * (2 * KIN) + 16 * ((kt * 4 + lq) ^ (m & 7)));
    }
#pragma unroll
    for (int r = 0; r < 2; r++)
#pragma unroll
      for (int c = 0; c < 4; c++)
        acc[r][c] = __builtin_amdgcn_mfma_f32_16x16x32_f16(wf[r], uf[c], acc[r][c], 0, 0, 0);
  }
  __builtin_amdgcn_s_setprio(0);
  __syncthreads();  // bar1: all stage-1 reads of A done
  // h1 -> R (row m, 512B stride, swizzled); bias + relu
#pragma unroll
  for (int r = 0; r < 2; r++) {
    int nbase = nb0 + 16 * r + lq * 4;
    float4 bv = *(const float4*)(b1 + nbase);
#pragma unroll
    for (int c = 0; c < 4; c++) {
      int m = 16 * c + l15;
      unsigned int h0 = f2h16(fmaxf(acc[r][c][0] + bv.x, 0.f));
      unsigned int h1v = f2h16(fmaxf(acc[r][c][1] + bv.y, 0.f));
      unsigned int h2v = f2h16(fmaxf(acc[r][c][2] + bv.z, 0.f));
      unsigned int h3 = f2h16(fmaxf(acc[r][c][3] + bv.w, 0.f));
      uint2 pk; pk.x = h0 | (h1v << 16); pk.y = h2v | (h3 << 16);
      int by = m * 512 + 16 * ((nbase >> 3) ^ (m & 7)) + ((nbase & 7) << 1);
      *(uint2*)(R + by) = pk;
    }
  }
  __syncthreads();  // bar2: h1 visible
  // ---- stage 2: vT[n][m] = (h1 @ W2)^T + b2 ----
  f32x4 acc2[2][4] = {};
  __builtin_amdgcn_s_setprio(1);
#pragma unroll 1
  for (int kt = 0; kt < 8; kt++) {
    f16x8 wf[2], hf[4];
#pragma unroll
    for (int r = 0; r < 2; r++)
      wf[r] = *(const f16x8*)(W2t + (long long)(nb0 + 16 * r + l15) * 256 + kt * 32 + lq * 8);
#pragma unroll
    for (int c = 0; c < 4; c++) {
      int m = 16 * c + l15;
      hf[c] = *(const f16x8*)(R + m * 512 + 16 * ((kt * 4 + lq) ^ (m & 7)));
    }
#pragma unroll
    for (int r = 0; r < 2; r++)
#pragma unroll
      for (int c = 0; c < 4; c++)
        acc2[r][c] = __builtin_amdgcn_mfma_f32_16x16x32_f16(wf[r], hf[c], acc2[r][c], 0, 0, 0);
  }
  __builtin_amdgcn_s_setprio(0);
  __syncthreads();  // bar3: all stage-2 reads of h1 done
  // v -> R ([m][n], swizzled); bias, no relu
#pragma unroll
  for (int r = 0; r < 2; r++) {
    int nbase = nb0 + 16 * r + lq * 4;
    float4 bv = *(const float4*)(b2 + nbase);
#pragma unroll
    for (int c = 0; c < 4; c++) {
      int m = 16 * c + l15;
      unsigned int h0 = f2h16(acc2[r][c][0] + bv.x);
      unsigned int h1v = f2h16(acc2[r][c][1] + bv.y);
      unsigned int h2v = f2h16(acc2[r][c][2] + bv.z);
      unsigned int h3 = f2h16(acc2[r][c][3] + bv.w);
      uint2 pk; pk.x = h0 | (h1v << 16); pk.y = h2v | (h3 << 16);
      int by = m * 512 + 16 * ((nbase >> 3) ^ (m & 7)) + ((nbase & 7) << 1);
      *(uint2*)(R + by) = pk;
    }
  }
  __syncthreads();  // bar4: v tile complete
  // coalesced store + BN partials. thread (c32, rg): rows rg*4..+3, cols c32*8..+7
  const int c32 = tid & 31, rg = tid >> 5;
  float s8[8] = {}, q8[8] = {};
#pragma unroll
  for (int k = 0; k < 4; k++) {
    int m = rg * 4 + k;
    uint4 vw = *(const uint4*)(R + m * 512 + 16 * (c32 ^ (m & 7)));
    long long grow = m0 + m;
    if (grow < M) {
      *(uint4*)(V + grow * 256 + c32 * 8) = vw;
      unsigned int ws[4] = {vw.x, vw.y, vw.z, vw.w};
#pragma unroll
      for (int kk = 0; kk < 8; kk++) {
        float xv = h2f((unsigned short)((ws[kk >> 1] >> ((kk & 1) * 16)) & 0xffff));
        s8[kk] += xv; q8[kk] += xv * xv;
      }
    }
  }
  __syncthreads();  // bar5: v reads done; R reusable as scratch
  float* shf = (float*)R;  // [256][17] sums + [256][17] sumsq = 34816 B
#pragma unroll
  for (int kk = 0; kk < 8; kk++) {
    int col = c32 * 8 + kk;
    shf[col * 17 + rg] = s8[kk];
    shf[4352 + col * 17 + rg] = q8[kk];
  }
  __syncthreads();  // bar6
  float* gb = gsum + (blockIdx.x & 31) * 512;  // 32-way banked accumulators
  if (tid < 256) {
    float tot = 0.f;
#pragma unroll
    for (int g = 0; g < 16; g++) tot += shf[tid * 17 + g];
    atomicAdd(&gb[tid], tot);
  } else {
    int col = tid - 256; float tot = 0.f;
#pragma unroll
    for (int g = 0; g < 16; g++) tot += shf[4352 + col * 17 + g];
    atomicAdd(&gb[256 + col], tot);
  }
}

// MFMA fp16 GEMM (predictor only). Tile 128x128, BK=32, 4 waves.
#define SA 40    // padded A/B staging stride (fp16)
#define SP 136   // padded C-tile stride (fp16)
__global__ __launch_bounds__(256) void gemm_k(
    const unsigned short* __restrict__ A, const unsigned short* __restrict__ Bt,
    const float* __restrict__ bias, unsigned short* __restrict__ C,
    int M, int K, int relu, float* __restrict__ gsum) {
  __shared__ __align__(16) unsigned short smem[128 * SP];
  unsigned short* As = smem;
  unsigned short* Bs = smem + 128 * SA;
  int m0 = blockIdx.x * 128, n0 = blockIdx.y * 128;
  int tid = threadIdx.x;
  int wave = tid >> 6, lane = tid & 63;
  int wm = (wave >> 1) * 64, wnn = (wave & 1) * 64;
  int lrow = lane & 15, lqq = lane >> 4;
  f32x4 acc[4][4] = {};
  int ktiles = K >> 5;
  int srow = tid >> 2;
  int ch8 = (tid & 3) << 3;
  int rowA0 = m0 + srow;      rowA0 = rowA0 < M ? rowA0 : M - 1;
  int rowA1 = m0 + srow + 64; rowA1 = rowA1 < M ? rowA1 : M - 1;
  const unsigned short* pa0 = A + (long long)rowA0 * K + ch8;
  const unsigned short* pa1 = A + (long long)rowA1 * K + ch8;
  const unsigned short* pq0 = Bt + (long long)(n0 + srow) * K + ch8;
  const unsigned short* pq1 = Bt + (long long)(n0 + srow + 64) * K + ch8;
  uint4 va0 = *(const uint4*)pa0, va1 = *(const uint4*)pa1;
  uint4 vb0 = *(const uint4*)pq0, vb1 = *(const uint4*)pq1;
  int lo0 = srow * SA + ch8, lo1 = (srow + 64) * SA + ch8;
  for (int kt = 0; kt < ktiles; ++kt) {
    __syncthreads();
    *(uint4*)(As + lo0) = va0;
    *(uint4*)(As + lo1) = va1;
    *(uint4*)(Bs + lo0) = vb0;
    *(uint4*)(Bs + lo1) = vb1;
    __syncthreads();
    f16x8 af[4], bf[4];
#pragma unroll
    for (int r = 0; r < 4; r++)
      af[r] = *(const f16x8*)(As + (wm + 16 * r + lrow) * SA + lqq * 8);
#pragma unroll
    for (int c = 0; c < 4; c++)
      bf[c] = *(const f16x8*)(Bs + (wnn + 16 * c + lrow) * SA + lqq * 8);
    if (kt + 1 < ktiles) {
      int kb = (kt + 1) << 5;
      va0 = *(const uint4*)(pa0 + kb); va1 = *(const uint4*)(pa1 + kb);
      vb0 = *(const uint4*)(pq0 + kb); vb1 = *(const uint4*)(pq1 + kb);
    }
#pragma unroll
    for (int r = 0; r < 4; r++)
#pragma unroll
      for (int c = 0; c < 4; c++)
        acc[r][c] = __builtin_amdgcn_mfma_f32_16x16x32_f16(af[r], bf[c], acc[r][c], 0, 0, 0);
  }
  __syncthreads();
  unsigned short* Ct = smem;
#pragma unroll
  for (int c = 0; c < 4; c++) {
    int col = wnn + 16 * c + lrow;
    float bv = bias[n0 + col];
#pragma unroll
    for (int r = 0; r < 4; r++) {
      int rbase = wm + 16 * r + lqq * 4;
#pragma unroll
      for (int i = 0; i < 4; i++) {
        float v = acc[r][c][i] + bv;
        if (relu) v = fmaxf(v, 0.f);
        Ct[(rbase + i) * SP + col] = f2h16(v);
      }
    }
  }
  __syncthreads();
  int c16 = tid & 15, g = tid >> 4;
  float s8[8] = {}, q8[8] = {};
  bool dostats = (gsum != nullptr);
#pragma unroll
  for (int i = 0; i < 8; i++) {
    int row = g + i * 16;
    int grow = m0 + row;
    uint4 vw = *(const uint4*)(Ct + row * SP + c16 * 8);
    if (grow < M) {
      *(uint4*)(C + (long long)grow * 256 + n0 + c16 * 8) = vw;
      if (dostats) {
        unsigned int ws[4] = {vw.x, vw.y, vw.z, vw.w};
#pragma unroll
        for (int k = 0; k < 8; k++) {
          float xv = h2f((unsigned short)((ws[k >> 1] >> ((k & 1) * 16)) & 0xffff));
          s8[k] += xv; q8[k] += xv * xv;
        }
      }
    }
  }
  if (dostats) {
    float* shf = (float*)smem;
    __syncthreads();
#pragma unroll
    for (int k = 0; k < 8; k++) shf[(c16 * 8 + k) * 17 + g] = s8[k];
    __syncthreads();
    if (tid < 128) {
      float t = 0.f;
#pragma unroll
      for (int gg = 0; gg < 16; gg++) t += shf[tid * 17 + gg];
      atomicAdd(&gsum[n0 + tid], t);
    }
    __syncthreads();
#pragma unroll
    for (int k = 0; k < 8; k++) shf[(c16 * 8 + k) * 17 + g] = q8[k];
    __syncthreads();
    if (tid < 128) {
      float t = 0.f;
#pragma unroll
      for (int gg = 0; gg < 16; gg++) t += shf[tid * 17 + gg];
      atomicAdd(&gsum[256 + n0 + tid], t);
    }
  }
}

__global__ void bn_finalize_k(const float* __restrict__ gsum,
                              const float* __restrict__ pg, const float* __restrict__ pb,
                              int Nn, float* __restrict__ scale, float* __restrict__ shift) {
  int f = threadIdx.x;
  float s = 0.f, q = 0.f;
#pragma unroll 4
  for (int b = 0; b < 32; b++) { s += gsum[b * 512 + f]; q += gsum[b * 512 + 256 + f]; }
  float inv = 1.f / (float)Nn;
  float mean = s * inv;
  float var = fmaxf(q * inv - mean * mean, 0.f);
  float sc = pg[f] * rsqrtf(var + 1e-5f);
  scale[f] = sc;
  shift[f] = pb[f] - mean * sc;
}

// fused pool: mean over graph rows of relu(v*sc+sh)
__global__ void pool_fused_k(const unsigned short* __restrict__ v, const float* __restrict__ scale,
                             const float* __restrict__ shift, const int* __restrict__ gstart,
                             unsigned short* __restrict__ gout) {
  int g = blockIdx.x, f = threadIdx.x;
  int s = gstart[g], e = gstart[g + 1];
  float sc = scale[f], sh = shift[f];
  float acc = 0.f;
  for (int r = s; r < e; r++) acc += fmaxf(h2f(v[(long long)r * 256 + f]) * sc + sh, 0.f);
  gout[(long long)g * 256 + f] = f2h16(acc / fmaxf((float)(e - s), 1.f));
}
__global__ void pred2_k(const unsigned short* __restrict__ p1, const void* __restrict__ Wp2,
                        const void* __restrict__ bp2, void* __restrict__ out, int G,
                        const int* __restrict__ flags) {
  int wf32 = flags[1];
  int idx = blockIdx.x * blockDim.x + threadIdx.x;
  if (idx >= G * 12) return;
  int g = idx / 12, t = idx - g * 12;
  float acc = lin(bp2, t, wf32);
  const unsigned short* row = p1 + (long long)g * 256;
  for (int k = 0; k < 256; k++) acc += h2f(row[k]) * lin(Wp2, k * 12 + t, wf32);
  if (wf32) ((float*)out)[idx] = acc;
  else      ((unsigned short*)out)[idx] = f2b(acc);
}

extern "C" void kernel_launch(void* const* d_in, const int* in_sizes, int n_in,
                              void* d_out, int out_size, void* d_ws, size_t ws_size,
                              hipStream_t stream) {
  int wb = -1;
  for (int i = 3; i + 15 < n_in; i++) {
    if (in_sizes[i] == 32768 && in_sizes[i + 1] == 256 && in_sizes[i + 2] == 65536 &&
        in_sizes[i + 3] == 256 && in_sizes[i + 4] == 256 && in_sizes[i + 5] == 256 &&
        in_sizes[i + 6] == 262144) { wb = i; break; }
  }
  if (wb < 0) wb = (n_in >= 20) ? 4 : 3;

  const void* x      = d_in[0];
  const int*  edge   = (const int*)d_in[1];
  const int*  batch  = (const int*)d_in[2];
  const void* W1_0   = d_in[wb + 0];
  const void* b1_0   = d_in[wb + 1];
  const void* W2_0   = d_in[wb + 2];
  const void* b2_0   = d_in[wb + 3];
  const void* gamma0 = d_in[wb + 4];
  const void* beta0  = d_in[wb + 5];
  const void* W1s    = d_in[wb + 6];
  const void* b1s    = d_in[wb + 7];
  const void* W2s    = d_in[wb + 8];
  const void* b2s    = d_in[wb + 9];
  const void* gammas = d_in[wb + 10];
  const void* betas  = d_in[wb + 11];
  const void* Wp1    = d_in[wb + 12];
  const void* bp1    = d_in[wb + 13];
  const void* Wp2    = d_in[wb + 14];
  const void* bp2    = d_in[wb + 15];

  const int N = in_sizes[0] / 128;
  const int E = in_sizes[1] / 2;
  const int G = out_size / 12;
  const int H = 256;

  char* w = (char*)d_ws;
  size_t off = 0;
  auto alloc = [&](size_t bytes) -> char* {
    char* p = w + off;
    off += (bytes + 255) & ~(size_t)255;
    return p;
  };
  unsigned short* bufX  = (unsigned short*)alloc((size_t)N * H * 2);
  unsigned short* bufY  = (unsigned short*)alloc((size_t)N * H * 2);  // xh parks here first
  unsigned short* w1_0t = (unsigned short*)alloc((size_t)128 * 256 * 2);
  unsigned short* w2_0t = (unsigned short*)alloc((size_t)256 * 256 * 2);
  unsigned short* w1st  = (unsigned short*)alloc((size_t)4 * 256 * 256 * 2);
  unsigned short* w2st  = (unsigned short*)alloc((size_t)4 * 256 * 256 * 2);
  unsigned short* wp1t  = (unsigned short*)alloc((size_t)256 * 256 * 2);
  int*   rowptr   = (int*)alloc((size_t)(N + 1) * 4);
  int*   cnt      = (int*)alloc((size_t)N * 4);
  int*   colidx   = (int*)alloc((size_t)E * 4);
  int*   partials = (int*)alloc(1024 * 4);
  float* gsum     = (float*)alloc(32 * 512 * 4);   // 32-way banked BN accum
  float* bnscale  = (float*)alloc(256 * 4);
  float* bnshift  = (float*)alloc(256 * 4);
  float* pg       = (float*)alloc(256 * 4);
  float* pb       = (float*)alloc(256 * 4);
  float* pb1      = (float*)alloc(256 * 4);
  float* pb2      = (float*)alloc(256 * 4);
  int*   gstart   = (int*)alloc((size_t)(G + 1) * 4);
  int*   flags    = (int*)alloc(256);
  unsigned short* gpool = (unsigned short*)alloc((size_t)G * H * 2);
  unsigned short* p1    = (unsigned short*)alloc((size_t)G * H * 2);
  (void)ws_size; (void)n_in;

  detect_k<<<1, 64, 0, stream>>>(edge, (const unsigned short*)x, flags);

  // x -> fp16 into bufY (dead once layer-0 fused kernel overwrites bufY)
  convert_k<<<(int)(((long long)N * 128 / 4 + 255) / 256), 256, 0, stream>>>(
      x, bufY, (long long)N * 128, flags);

  dim3 tb(32, 8);
  auto transpose = [&](const void* src, long long eoff, unsigned short* dst, int R, int C) {
    transpose_off_k<<<dim3((C + 31) / 32, (R + 31) / 32), tb, 0, stream>>>(src, eoff, dst, R, C, flags);
  };
  transpose(W1_0, 0, w1_0t, 128, 256);
  transpose(W2_0, 0, w2_0t, 256, 256);
  for (int i = 0; i < 4; i++) {
    transpose(W1s, (long long)i * 65536, w1st + i * 65536, 256, 256);
    transpose(W2s, (long long)i * 65536, w2st + i * 65536, 256, 256);
  }
  transpose(Wp1, 0, wp1t, 256, 256);

  // CSR
  zero_i32_k<<<(N + 255) / 256, 256, 0, stream>>>(cnt, N);
  hist_k<<<(E + 255) / 256, 256, 0, stream>>>(edge, E, cnt, flags);
  int NB = (N + SCAN_CHUNK - 1) / SCAN_CHUNK;
  scan1_k<<<NB, 256, 0, stream>>>(cnt, rowptr, partials, N);
  scan2_k<<<1, 256, 0, stream>>>(partials, NB);
  scan3_k<<<NB, 256, 0, stream>>>(rowptr, partials, N, E);
  zero_i32_k<<<(N + 255) / 256, 256, 0, stream>>>(cnt, N);
  fill_k<<<(E + 255) / 256, 256, 0, stream>>>(edge, E, rowptr, cnt, colidx, flags);
  graph_bounds_k<<<(G + 1 + 255) / 256, 256, 0, stream>>>(batch, N, G, gstart, flags);

  const int ntiles = (N + 63) / 64;
  auto fused = [&](const unsigned short* Au, const unsigned short* w1, const unsigned short* w2,
                   unsigned short* Vv, int K) {
    if (K == 128)
      fused_layer_k<128><<<ntiles, 512, 0, stream>>>(Au, w1, w2, pb1, pb2, Vv, N, gsum);
    else
      fused_layer_k<256><<<ntiles, 512, 0, stream>>>(Au, w1, w2, pb1, pb2, Vv, N, gsum);
  };

  // ---- layer 0 ----
  prep_k<<<1, 256, 0, stream>>>(b1_0, b2_0, gamma0, beta0, 0, pb1, pb2, pg, pb, gsum, flags);
  gather_fused_k<16, 0><<<(N * 16 + 255) / 256, 256, 0, stream>>>(
      bufY, bnscale, bnshift, rowptr, colidx, bufX, N);
  fused(bufX, w1_0t, w2_0t, bufY, 128);   // v0 + fused BN stats -> bufY
  bn_finalize_k<<<1, 256, 0, stream>>>(gsum, pg, pb, N, bnscale, bnshift);
  unsigned short* cur = bufY;  // pre-BN v0
  unsigned short* oth = bufX;
  // ---- layers 1..4 ----
  for (int i = 0; i < 4; i++) {
    prep_k<<<1, 256, 0, stream>>>(b1s, b2s, gammas, betas, i * 256, pb1, pb2, pg, pb, gsum, flags);
    gather_fused_k<32, 1><<<(N * 32 + 255) / 256, 256, 0, stream>>>(
        cur, bnscale, bnshift, rowptr, colidx, oth, N);
    fused(oth, w1st + i * 65536, w2st + i * 65536, cur, 256);  // v_i + BN stats -> cur
    bn_finalize_k<<<1, 256, 0, stream>>>(gsum, pg, pb, N, bnscale, bnshift);
  }

  // ---- pool + predictor ----
  copy256_k<<<1, 256, 0, stream>>>(bp1, 0, pb1, flags);
  pool_fused_k<<<G, 256, 0, stream>>>(cur, bnscale, bnshift, gstart, gpool);
  gemm_k<<<dim3((G + 127) / 128, 2), 256, 0, stream>>>(gpool, wp1t, pb1, p1, G, 256, 1, nullptr);
  pred2_k<<<(G * 12 + 255) / 256, 256, 0, stream>>>(p1, Wp2, bp2, d_out, G, flags);
}